// Round 5
// baseline (264.305 us; speedup 1.0000x reference)
//
#include <hip/hip_runtime.h>
#include <hip/hip_bf16.h>

typedef __attribute__((ext_vector_type(8))) short sh8;
typedef __attribute__((ext_vector_type(4))) short sh4;
typedef __attribute__((ext_vector_type(4))) float f4v;
typedef __attribute__((ext_vector_type(4))) unsigned u4v;
typedef __attribute__((ext_vector_type(2))) unsigned u2v;

#define SCALE_Q 0.1803368801f   // 0.125 * log2(e): folds softmax scale AND exp->exp2

__device__ __forceinline__ short f2bf(float f) {
    unsigned u = __builtin_bit_cast(unsigned, f);
    u += 0x7fffu + ((u >> 16) & 1u);   // RNE
    return (short)(u >> 16);
}

#if __has_builtin(__builtin_amdgcn_cvt_pk_bf16_f32)
__device__ __forceinline__ unsigned pk_bf16(float a, float b) {
    return __builtin_bit_cast(unsigned, __builtin_amdgcn_cvt_pk_bf16_f32(a, b));
}
#else
__device__ __forceinline__ unsigned pk_bf16(float a, float b) {
    return (unsigned)(unsigned short)f2bf(a) | ((unsigned)(unsigned short)f2bf(b) << 16);
}
#endif

#if __has_builtin(__builtin_amdgcn_exp2f)
#define EXP2(x) __builtin_amdgcn_exp2f(x)
#else
#define EXP2(x) exp2f(x)
#endif

__device__ __forceinline__ void glds16(const short* g, short* l) {
    __builtin_amdgcn_global_load_lds(
        (const __attribute__((address_space(1))) void*)g,
        (__attribute__((address_space(3))) void*)l, 16, 0, 0);
}

// ---------------- pack: fp32 -> bf16 conversions + weight fusion ----------------
// vec4 regions: x->xb | Wq->Wqkb(scaled) | Wk->Wqkb+1M | Wv->Wvb | Wo->Wob | biases
__global__ __launch_bounds__(256)
void pack_all(const float* __restrict__ x,  const float* __restrict__ Wq,
              const float* __restrict__ Wk, const float* __restrict__ Wv,
              const float* __restrict__ Wo, const float* __restrict__ bq,
              const float* __restrict__ bk, const float* __restrict__ bv,
              short* __restrict__ xb, short* __restrict__ Wqkb,
              short* __restrict__ Wvb, short* __restrict__ Wob,
              float* __restrict__ bqk, float* __restrict__ bvf)
{
    const long idx = (long)blockIdx.x * 256 + threadIdx.x;
    if (idx >= 2752896) return;
    const float* src; short* dst; float sc = 1.0f; long off;
    if (idx < 2097152)       { off = idx;           src = x;  dst = xb; }
    else if (idx < 2359296)  { off = idx - 2097152; src = Wq; dst = Wqkb;           sc = SCALE_Q; }
    else if (idx < 2424832)  { off = idx - 2359296; src = Wk; dst = Wqkb + 1048576; }
    else if (idx < 2490368)  { off = idx - 2424832; src = Wv; dst = Wvb; }
    else if (idx < 2752512)  { off = idx - 2490368; src = Wo; dst = Wob; }
    else {
        long j = idx - 2752512;  // 0..383
        const float* bs; float* bd; float s2 = 1.0f;
        if (j < 256)      { bs = bq + j * 4;         bd = bqk + j * 4;          s2 = SCALE_Q; }
        else if (j < 320) { bs = bk + (j - 256) * 4; bd = bqk + 1024 + (j - 256) * 4; }
        else              { bs = bv + (j - 320) * 4; bd = bvf + (j - 320) * 4; }
        f4v v = *reinterpret_cast<const f4v*>(bs);
        f4v o = { v[0] * s2, v[1] * s2, v[2] * s2, v[3] * s2 };
        *reinterpret_cast<f4v*>(bd) = o;
        return;
    }
    f4v v = *reinterpret_cast<const f4v*>(src + off * 4);
    sh4 o; o[0] = f2bf(v[0] * sc); o[1] = f2bf(v[1] * sc);
    o[2] = f2bf(v[2] * sc); o[3] = f2bf(v[3] * sc);
    *reinterpret_cast<sh4*>(dst + off * 4) = o;
}

// ---------------- fused projection: QK GEMM + V-transposed GEMM, one grid ----------------
// Blocks 0..639:   QKb[8192][1280] = xb[8192][1024] · Wqkb[1280][1024]^T + bqk (col bias)
// Blocks 640..767: Vt [256][8192]  = Wvb[256][1024] · xb[8192][1024]^T  + bvf (row bias)
//   (swapped operands make the token axis the store-lane axis -> coalesced Vt, no scatter)
// Grid 768 = 3 x 256: zero tail. K=1024, 128x128 tiles, m97-style glds staging.
__global__ __launch_bounds__(256)
void proj_fused(const short* __restrict__ xb, const short* __restrict__ Wqkb,
                const float* __restrict__ bqk, short* __restrict__ QKb,
                const short* __restrict__ Wvb, const float* __restrict__ bvf,
                short* __restrict__ Vt)
{
    constexpr int K = 1024;
    __shared__ __attribute__((aligned(16))) short As[128 * 32];
    __shared__ __attribute__((aligned(16))) short Bs[128 * 32];

    const int t = threadIdx.x, lane = t & 63, w = t >> 6;
    const int lr = lane & 15, quad = lane >> 4;
    const int wm = (w >> 1) * 64, wn = (w & 1) * 64;
    const int sr = lane >> 2, sc = lane & 3;

    const int id = blockIdx.x;
    const short *A, *B; const float* bias; short* C;
    int m0, n0, N; bool brow;
    if (id < 640) {
        A = xb;  B = Wqkb; bias = bqk; C = QKb; N = 1280;
        m0 = (id / 10) * 128; n0 = (id % 10) * 128; brow = false;
    } else {
        const int v = id - 640;
        A = Wvb; B = xb;   bias = bvf; C = Vt;  N = 8192;
        m0 = (v >> 6) * 128; n0 = (v & 63) * 128; brow = true;
    }

    f4v acc[4][4] = {};

    for (int kb = 0; kb < K; kb += 32) {
#pragma unroll
        for (int p = 0; p < 2; ++p) {
            const int s = 2 * w + p;
            const int r = s * 16 + sr;
            const int g = sc ^ ((r >> 1) & 3);
            glds16(A + (size_t)(m0 + r) * K + kb + g * 8, &As[s * 512]);
            glds16(B + (size_t)(n0 + r) * K + kb + g * 8, &Bs[s * 512]);
        }
        __syncthreads();
        sh8 af[4], bfr[4];
#pragma unroll
        for (int i = 0; i < 4; ++i) {
            const int ra = wm + i * 16 + lr;
            af[i] = *reinterpret_cast<const sh8*>(&As[ra * 32 + ((quad ^ ((ra >> 1) & 3)) << 3)]);
            const int rb = wn + i * 16 + lr;
            bfr[i] = *reinterpret_cast<const sh8*>(&Bs[rb * 32 + ((quad ^ ((rb >> 1) & 3)) << 3)]);
        }
#pragma unroll
        for (int mi = 0; mi < 4; ++mi)
#pragma unroll
            for (int ni = 0; ni < 4; ++ni)
                acc[mi][ni] = __builtin_amdgcn_mfma_f32_16x16x32_bf16(af[mi], bfr[ni], acc[mi][ni], 0, 0, 0);
        __syncthreads();
    }

#pragma unroll
    for (int mi = 0; mi < 4; ++mi) {
        const int row = m0 + wm + mi * 16 + quad * 4;
        f4v br4 = {};
        if (brow) br4 = *reinterpret_cast<const f4v*>(&bias[row]);
#pragma unroll
        for (int ni = 0; ni < 4; ++ni) {
            const int col = n0 + wn + ni * 16 + lr;
            const float bc = brow ? 0.f : bias[col];
#pragma unroll
            for (int i = 0; i < 4; ++i) {
                const float v = acc[mi][ni][i] + (brow ? br4[i] : bc);
                C[(size_t)(row + i) * N + col] = f2bf(v);
            }
        }
    }
}

// ---------------- O-projection GEMM: out[M,N] = A[M,K] · W[N,K]^T + bias (fp32 out) ----------------
__global__ __launch_bounds__(256)
void gemm_out(const short* __restrict__ A, const short* __restrict__ B,
              const float* __restrict__ bias, float* __restrict__ Cv,
              int M, int N, int K)
{
    __shared__ __attribute__((aligned(16))) short As[128 * 32];
    __shared__ __attribute__((aligned(16))) short Bs[128 * 32];

    const int t = threadIdx.x, lane = t & 63, w = t >> 6;
    const int lr = lane & 15, quad = lane >> 4;
    const int m0 = blockIdx.y * 128, n0 = blockIdx.x * 128;
    const int wm = (w >> 1) * 64, wn = (w & 1) * 64;
    const int sr = lane >> 2, sc = lane & 3;

    f4v acc[4][4] = {};

    for (int kb = 0; kb < K; kb += 32) {
#pragma unroll
        for (int p = 0; p < 2; ++p) {
            const int s = 2 * w + p;
            const int r = s * 16 + sr;
            const int g = sc ^ ((r >> 1) & 3);
            glds16(A + (size_t)(m0 + r) * K + kb + g * 8, &As[s * 512]);
            glds16(B + (size_t)(n0 + r) * K + kb + g * 8, &Bs[s * 512]);
        }
        __syncthreads();
        sh8 af[4], bfr[4];
#pragma unroll
        for (int i = 0; i < 4; ++i) {
            const int ra = wm + i * 16 + lr;
            af[i] = *reinterpret_cast<const sh8*>(&As[ra * 32 + ((quad ^ ((ra >> 1) & 3)) << 3)]);
            const int rb = wn + i * 16 + lr;
            bfr[i] = *reinterpret_cast<const sh8*>(&Bs[rb * 32 + ((quad ^ ((rb >> 1) & 3)) << 3)]);
        }
#pragma unroll
        for (int mi = 0; mi < 4; ++mi)
#pragma unroll
            for (int ni = 0; ni < 4; ++ni)
                acc[mi][ni] = __builtin_amdgcn_mfma_f32_16x16x32_bf16(af[mi], bfr[ni], acc[mi][ni], 0, 0, 0);
        __syncthreads();
    }

#pragma unroll
    for (int ni = 0; ni < 4; ++ni) {
        const int col = n0 + wn + ni * 16 + lr;
        const float bv = bias[col];
#pragma unroll
        for (int mi = 0; mi < 4; ++mi) {
            const int row = m0 + wm + mi * 16 + quad * 4;
#pragma unroll
            for (int i = 0; i < 4; ++i)
                Cv[(size_t)(row + i) * N + col] = acc[mi][ni][i] + bv;
        }
    }
}

// ---------------- flash attention: S^T/O^T formulation, P in registers ----------------
// QKb [8192][1280]: Q cols 0..1023 (pre-scaled by 0.125*log2e), K cols 1024..1279.
// Vt [256][8192]: V^T, token-contiguous rows.
// R4 post-mortem: R2-R4 all plateau at 93-95us with identical per-wave LDS traffic
// (each wave reads the full 32KB K+V tile for only 16 q-cols; 4.2M ds_read_b128
// total ~= 82us of LDS pipe at m134's 12cy/b128 -> LDS-read-pipe-bound).
// R5: 32 q-cols per wave (nt dimension back) -> every K/V fragment read serves
// 2x the q-work -> LDS traffic halves (R1's level) while KEEPING 8-wave/512-thread
// blocks (grid 8x16x4 = 512 = exactly 2 blocks/CU, 16 waves/CU residency; R1's
// 4-wave blocks only reached ~6 waves/CU). __launch_bounds__(512,4) pins VGPR<=128
// so residency cannot silently drop to 1 block/CU. Staging/swizzle/vmcnt ledger
// unchanged from R4 (verified): Ks dbuf + counted vmcnt(2), Vs single-buffered
// staged after the release barrier, hoisted base+immediate LDS reads.
__global__ __launch_bounds__(512, 4)
void flash_attn(const short* __restrict__ QKb, const short* __restrict__ Vt,
                short* __restrict__ Og)
{
    constexpr int L = 2048, LQ = 1280, HD = 64;
    constexpr int NT = L / 128;                              // 16 key-tiles of 128
    // layout: Ks0 [0,8192) | Ks1 [8192,16384) | Vs [16384,24576)  (shorts) = 48 KB
    __shared__ __attribute__((aligned(16))) short smem[3 * 8192];

    const int t = threadIdx.x, lane = t & 63, w = t >> 6;    // w = 0..7
    const int lr = lane & 15, quad = lane >> 4;
    const int qt = blockIdx.x, h = blockIdx.y, b = blockIdx.z;
    const int kh = h >> 2;
    const int q0 = qt * 256;                                 // block covers 256 q-cols
    const int kcol = 1024 + kh * HD;

    // Q B-frags (wave owns q-cols q0 + w*32 .. w*32+31 of S^T / O^T)
    sh8 qf[2][2];
#pragma unroll
    for (int nt = 0; nt < 2; ++nt)
#pragma unroll
        for (int ks = 0; ks < 2; ++ks)
            qf[nt][ks] = *reinterpret_cast<const sh8*>(
                QKb + (size_t)(b * L + q0 + w * 32 + nt * 16 + lr) * LQ + h * HD + ks * 32 + quad * 8);

    f4v oT[4][2] = {};
    f4v lacc[2] = {};                                // denominator via MFMA ones-row
    sh8 ones;
#pragma unroll
    for (int i = 0; i < 8; ++i) ones[i] = (short)0x3F80;   // bf16 1.0

    // hoisted LDS read bases: lane-dependent, tile-invariant. All per-tile reads
    // are base + compile-time immediate (Ks: +buf*16KB +(half*4+nl)*2KB; Vs: +m*4KB).
    const int f7 = lr & 7, f15 = lr & 15;
    const short* const Ka0 = &smem[lr * 64 + ((quad ^ f7) << 3)];
    const short* const Ka1 = &smem[lr * 64 + (((4 + quad) ^ f7) << 3)];
    const short* const Vr[4] = {
        &smem[16384 + lr * 128 + (((0  + quad) ^ f15) << 3)],
        &smem[16384 + lr * 128 + (((4  + quad) ^ f15) << 3)],
        &smem[16384 + lr * 128 + (((8  + quad) ^ f15) << 3)],
        &smem[16384 + lr * 128 + (((12 + quad) ^ f15) << 3)] };

    // staging pointers, advanced by fixed stride per tile (no per-tile addr rebuild)
    const int r8 = lane >> 3, g8 = lane & 7;        // K staging: row-in-seg, chunk
    const int v_r4 = lane >> 4, v_g = lane & 15;    // V staging: row-in-seg, chunk
    const short* Vbase = Vt + (size_t)kh * HD * 8192;
    const short* Kp[2];
    const short* Vp[2];
#pragma unroll
    for (int p = 0; p < 2; ++p) {
        const int s = 2 * w + p;
        const int rk = s * 8 + r8;                   // perm-row 0..127
        const int mm = rk & 15;
        const int key = ((rk >> 5) << 5) + ((mm >> 2) << 3) + (((rk >> 4) & 1) << 2) + (mm & 3);
        const int gk = g8 ^ (rk & 7);
        Kp[p] = QKb + (size_t)(b * L + key) * LQ + kcol + gk * 8;
        const int rv = s * 4 + v_r4;                 // d-row 0..63
        const int gv = v_g ^ (rv & 15);
        Vp[p] = Vbase + (size_t)rv * 8192 + b * L + gv * 8;
    }

    // Ks [128 perm-rows][64 d] (swz ^(r&7)), double-buffered; 2 glds16/thread
    auto stageK = [&](int buf) {
#pragma unroll
        for (int p = 0; p < 2; ++p) {
            glds16(Kp[p], &smem[buf * 8192 + (2 * w + p) * 512]);
            Kp[p] += 128 * LQ;                       // next 128 keys (token rows)
        }
    };
    // Vs [64 d][128 keys] (swz ^(r&15)), single-buffered; 2 glds16/thread
    auto stageV = [&]() {
#pragma unroll
        for (int p = 0; p < 2; ++p) {
            glds16(Vp[p], &smem[16384 + (2 * w + p) * 512]);
            Vp[p] += 128;                            // next 128 keys (within V^T row)
        }
    };

    auto body = [&](int buf, int kt) {
        if (kt + 1 < NT) {
            stageK(buf ^ 1);                         // issue next K-tile early
            // outstanding (oldest->newest): K(kt)2, V(kt)2, K(kt+1)2 -> wait cur tile
            asm volatile("s_waitcnt vmcnt(2)" ::: "memory");
        } else {
            asm volatile("s_waitcnt vmcnt(0)" ::: "memory");
        }
        __builtin_amdgcn_s_barrier();                // publish: tile kt (Ks+Vs) ready
        asm volatile("" ::: "memory");

        const int kb = buf * 8192;                   // compile-time after unroll

#pragma unroll
        for (int half = 0; half < 2; ++half) {
            // S^T = K·Q^T for keys [half*64, half*64+64) x 32 q-cols
            f4v st[4][2] = {};
            __builtin_amdgcn_s_setprio(1);
#pragma unroll
            for (int nl = 0; nl < 4; ++nl) {
                sh8 a0 = *reinterpret_cast<const sh8*>(Ka0 + kb + (half * 4 + nl) * 1024);
                sh8 a1 = *reinterpret_cast<const sh8*>(Ka1 + kb + (half * 4 + nl) * 1024);
#pragma unroll
                for (int nt = 0; nt < 2; ++nt) {
                    st[nl][nt] = __builtin_amdgcn_mfma_f32_16x16x32_bf16(a0, qf[nt][0], st[nl][nt], 0, 0, 0);
                    st[nl][nt] = __builtin_amdgcn_mfma_f32_16x16x32_bf16(a1, qf[nt][1], st[nl][nt], 0, 0, 0);
                }
            }
            __builtin_amdgcn_s_setprio(0);

            // exp2 -> P^T B-frags in registers -> PV MFMA (+ l via ones-row MFMA)
            // vf[4] loaded once per cl, reused for BOTH nt -> V LDS traffic halved
#pragma unroll
            for (int cl = 0; cl < 2; ++cl) {
                const int c = half * 2 + cl;
                sh8 vf[4];
#pragma unroll
                for (int m = 0; m < 4; ++m)
                    vf[m] = *reinterpret_cast<const sh8*>(Vr[c] + m * 2048);
#pragma unroll
                for (int nt = 0; nt < 2; ++nt) {
                    f4v e0, e1;
#pragma unroll
                    for (int i = 0; i < 4; ++i) {
                        e0[i] = EXP2(st[2 * cl][nt][i]);
                        e1[i] = EXP2(st[2 * cl + 1][nt][i]);
                    }
                    u4v pu = { pk_bf16(e0[0], e0[1]), pk_bf16(e0[2], e0[3]),
                               pk_bf16(e1[0], e1[1]), pk_bf16(e1[2], e1[3]) };
                    sh8 pf = __builtin_bit_cast(sh8, pu);
                    __builtin_amdgcn_s_setprio(1);
                    lacc[nt] = __builtin_amdgcn_mfma_f32_16x16x32_bf16(ones, pf, lacc[nt], 0, 0, 0);
#pragma unroll
                    for (int m = 0; m < 4; ++m)
                        oT[m][nt] = __builtin_amdgcn_mfma_f32_16x16x32_bf16(vf[m], pf, oT[m][nt], 0, 0, 0);
                    __builtin_amdgcn_s_setprio(0);
                }
            }
        }

        asm volatile("" ::: "memory");               // reads done before release
        __builtin_amdgcn_s_barrier();                // release: Ks[buf^1] + Vs writable
        asm volatile("" ::: "memory");
        if (kt + 1 < NT) stageV();                   // stage V(kt+1) into Vs
    };

    stageK(0);                                       // prologue prefetch
    stageV();
#pragma unroll 1
    for (int kt = 0; kt < NT; kt += 2) {
        body(0, kt);
        body(1, kt + 1);
    }

    // normalize + store O^T -> Og[token][h*64+d].  l = lacc[nt][i] (rows identical).
#pragma unroll
    for (int nt = 0; nt < 2; ++nt) {
        const float inv = 1.0f / lacc[nt][0];
        const size_t tok = (size_t)b * L + q0 + w * 32 + nt * 16 + lr;
        short* op = Og + tok * 1024 + h * HD + quad * 4;
#pragma unroll
        for (int m = 0; m < 4; ++m) {
            u2v pk2 = { pk_bf16(oT[m][nt][0] * inv, oT[m][nt][1] * inv),
                        pk_bf16(oT[m][nt][2] * inv, oT[m][nt][3] * inv) };
            *reinterpret_cast<u2v*>(op + m * 16) = pk2;
        }
    }
}

extern "C" void kernel_launch(void* const* d_in, const int* in_sizes, int n_in,
                              void* d_out, int out_size, void* d_ws, size_t ws_size,
                              hipStream_t stream)
{
    (void)in_sizes; (void)n_in; (void)out_size; (void)ws_size;
    const float* x  = (const float*)d_in[0];
    const float* Wq = (const float*)d_in[1];
    const float* bq = (const float*)d_in[2];
    const float* Wk = (const float*)d_in[3];
    const float* bk = (const float*)d_in[4];
    const float* Wv = (const float*)d_in[5];
    const float* bv = (const float*)d_in[6];
    const float* Wo = (const float*)d_in[7];
    const float* bo = (const float*)d_in[8];
    float* out = (float*)d_out;

    char* ws = (char*)d_ws;
    short* xb   = (short*)(ws);                     // 8192x1024 bf16 = 16 MB
    short* Ob   = (short*)(ws);                     // aliases xb (dead after proj)
    short* Wqkb = (short*)(ws + 16777216);          // 1280x1024 bf16 = 2.5 MB
    short* Wvb  = (short*)(ws + 19398656);          // 256x1024 bf16 = 512 KB
    short* Wob  = (short*)(ws + 19922944);          // 1024x1024 bf16 = 2 MB
    float* bqk  = (float*)(ws + 22020096);          // 1280 fp32
    float* bvf  = (float*)(ws + 22025216);          // 256 fp32
    short* Vt   = (short*)(ws + 25165824);          // 256x8192 bf16 = 4 MB (V^T)
    short* QKb  = (short*)d_out;                    // 8192x1280 bf16 = 20 MB scratch

    pack_all<<<10754, 256, 0, stream>>>(x, Wq, Wk, Wv, Wo, bq, bk, bv,
                                        xb, Wqkb, Wvb, Wob, bqk, bvf);
    proj_fused<<<768, 256, 0, stream>>>(xb, Wqkb, bqk, QKb, Wvb, bvf, Vt);
    flash_attn<<<dim3(8, 16, 4), 512, 0, stream>>>(QKb, Vt, Ob);
    gemm_out<<<dim3(8, 64), 256, 0, stream>>>(Ob, Wob, bo, out, 8192, 1024, 1024);
}

// Round 6
// 255.049 us; speedup vs baseline: 1.0363x; 1.0363x over previous
//
#include <hip/hip_runtime.h>
#include <hip/hip_bf16.h>

typedef __attribute__((ext_vector_type(8))) short sh8;
typedef __attribute__((ext_vector_type(4))) short sh4;
typedef __attribute__((ext_vector_type(4))) float f4v;
typedef __attribute__((ext_vector_type(4))) unsigned u4v;
typedef __attribute__((ext_vector_type(2))) unsigned u2v;

#define SCALE_Q 0.1803368801f   // 0.125 * log2(e): folds softmax scale AND exp->exp2

__device__ __forceinline__ short f2bf(float f) {
    unsigned u = __builtin_bit_cast(unsigned, f);
    u += 0x7fffu + ((u >> 16) & 1u);   // RNE
    return (short)(u >> 16);
}

#if __has_builtin(__builtin_amdgcn_cvt_pk_bf16_f32)
__device__ __forceinline__ unsigned pk_bf16(float a, float b) {
    return __builtin_bit_cast(unsigned, __builtin_amdgcn_cvt_pk_bf16_f32(a, b));
}
#else
__device__ __forceinline__ unsigned pk_bf16(float a, float b) {
    return (unsigned)(unsigned short)f2bf(a) | ((unsigned)(unsigned short)f2bf(b) << 16);
}
#endif

#if __has_builtin(__builtin_amdgcn_exp2f)
#define EXP2(x) __builtin_amdgcn_exp2f(x)
#else
#define EXP2(x) exp2f(x)
#endif

__device__ __forceinline__ void glds16(const short* g, short* l) {
    __builtin_amdgcn_global_load_lds(
        (const __attribute__((address_space(1))) void*)g,
        (__attribute__((address_space(3))) void*)l, 16, 0, 0);
}

// ---------------- pack: fp32 -> bf16 conversions + weight fusion ----------------
// vec4 regions: x->xb | Wq->Wqkb(scaled) | Wk->Wqkb+1M | Wv->Wvb | Wo->Wob | biases
__global__ __launch_bounds__(256)
void pack_all(const float* __restrict__ x,  const float* __restrict__ Wq,
              const float* __restrict__ Wk, const float* __restrict__ Wv,
              const float* __restrict__ Wo, const float* __restrict__ bq,
              const float* __restrict__ bk, const float* __restrict__ bv,
              short* __restrict__ xb, short* __restrict__ Wqkb,
              short* __restrict__ Wvb, short* __restrict__ Wob,
              float* __restrict__ bqk, float* __restrict__ bvf)
{
    const long idx = (long)blockIdx.x * 256 + threadIdx.x;
    if (idx >= 2752896) return;
    const float* src; short* dst; float sc = 1.0f; long off;
    if (idx < 2097152)       { off = idx;           src = x;  dst = xb; }
    else if (idx < 2359296)  { off = idx - 2097152; src = Wq; dst = Wqkb;           sc = SCALE_Q; }
    else if (idx < 2424832)  { off = idx - 2359296; src = Wk; dst = Wqkb + 1048576; }
    else if (idx < 2490368)  { off = idx - 2424832; src = Wv; dst = Wvb; }
    else if (idx < 2752512)  { off = idx - 2490368; src = Wo; dst = Wob; }
    else {
        long j = idx - 2752512;  // 0..383
        const float* bs; float* bd; float s2 = 1.0f;
        if (j < 256)      { bs = bq + j * 4;         bd = bqk + j * 4;          s2 = SCALE_Q; }
        else if (j < 320) { bs = bk + (j - 256) * 4; bd = bqk + 1024 + (j - 256) * 4; }
        else              { bs = bv + (j - 320) * 4; bd = bvf + (j - 320) * 4; }
        f4v v = *reinterpret_cast<const f4v*>(bs);
        f4v o = { v[0] * s2, v[1] * s2, v[2] * s2, v[3] * s2 };
        *reinterpret_cast<f4v*>(bd) = o;
        return;
    }
    f4v v = *reinterpret_cast<const f4v*>(src + off * 4);
    sh4 o; o[0] = f2bf(v[0] * sc); o[1] = f2bf(v[1] * sc);
    o[2] = f2bf(v[2] * sc); o[3] = f2bf(v[3] * sc);
    *reinterpret_cast<sh4*>(dst + off * 4) = o;
}

// ---------------- fused projection: QK GEMM + V-transposed GEMM, one grid ----------------
// Blocks 0..639:   QKb[8192][1280] = xb[8192][1024] · Wqkb[1280][1024]^T + bqk (col bias)
// Blocks 640..767: Vt [256][8192]  = Wvb[256][1024] · xb[8192][1024]^T  + bvf (row bias)
//   (swapped operands make the token axis the store-lane axis -> coalesced Vt, no scatter)
// Grid 768 = 3 x 256: zero tail. K=1024, 128x128 tiles, m97-style glds staging.
__global__ __launch_bounds__(256)
void proj_fused(const short* __restrict__ xb, const short* __restrict__ Wqkb,
                const float* __restrict__ bqk, short* __restrict__ QKb,
                const short* __restrict__ Wvb, const float* __restrict__ bvf,
                short* __restrict__ Vt)
{
    constexpr int K = 1024;
    __shared__ __attribute__((aligned(16))) short As[128 * 32];
    __shared__ __attribute__((aligned(16))) short Bs[128 * 32];

    const int t = threadIdx.x, lane = t & 63, w = t >> 6;
    const int lr = lane & 15, quad = lane >> 4;
    const int wm = (w >> 1) * 64, wn = (w & 1) * 64;
    const int sr = lane >> 2, sc = lane & 3;

    const int id = blockIdx.x;
    const short *A, *B; const float* bias; short* C;
    int m0, n0, N; bool brow;
    if (id < 640) {
        A = xb;  B = Wqkb; bias = bqk; C = QKb; N = 1280;
        m0 = (id / 10) * 128; n0 = (id % 10) * 128; brow = false;
    } else {
        const int v = id - 640;
        A = Wvb; B = xb;   bias = bvf; C = Vt;  N = 8192;
        m0 = (v >> 6) * 128; n0 = (v & 63) * 128; brow = true;
    }

    f4v acc[4][4] = {};

    for (int kb = 0; kb < K; kb += 32) {
#pragma unroll
        for (int p = 0; p < 2; ++p) {
            const int s = 2 * w + p;
            const int r = s * 16 + sr;
            const int g = sc ^ ((r >> 1) & 3);
            glds16(A + (size_t)(m0 + r) * K + kb + g * 8, &As[s * 512]);
            glds16(B + (size_t)(n0 + r) * K + kb + g * 8, &Bs[s * 512]);
        }
        __syncthreads();
        sh8 af[4], bfr[4];
#pragma unroll
        for (int i = 0; i < 4; ++i) {
            const int ra = wm + i * 16 + lr;
            af[i] = *reinterpret_cast<const sh8*>(&As[ra * 32 + ((quad ^ ((ra >> 1) & 3)) << 3)]);
            const int rb = wn + i * 16 + lr;
            bfr[i] = *reinterpret_cast<const sh8*>(&Bs[rb * 32 + ((quad ^ ((rb >> 1) & 3)) << 3)]);
        }
#pragma unroll
        for (int mi = 0; mi < 4; ++mi)
#pragma unroll
            for (int ni = 0; ni < 4; ++ni)
                acc[mi][ni] = __builtin_amdgcn_mfma_f32_16x16x32_bf16(af[mi], bfr[ni], acc[mi][ni], 0, 0, 0);
        __syncthreads();
    }

#pragma unroll
    for (int mi = 0; mi < 4; ++mi) {
        const int row = m0 + wm + mi * 16 + quad * 4;
        f4v br4 = {};
        if (brow) br4 = *reinterpret_cast<const f4v*>(&bias[row]);
#pragma unroll
        for (int ni = 0; ni < 4; ++ni) {
            const int col = n0 + wn + ni * 16 + lr;
            const float bc = brow ? 0.f : bias[col];
#pragma unroll
            for (int i = 0; i < 4; ++i) {
                const float v = acc[mi][ni][i] + (brow ? br4[i] : bc);
                C[(size_t)(row + i) * N + col] = f2bf(v);
            }
        }
    }
}

// ---------------- O-projection GEMM: out[M,N] = A[M,K] · W[N,K]^T + bias (fp32 out) ----------------
__global__ __launch_bounds__(256)
void gemm_out(const short* __restrict__ A, const short* __restrict__ B,
              const float* __restrict__ bias, float* __restrict__ Cv,
              int M, int N, int K)
{
    __shared__ __attribute__((aligned(16))) short As[128 * 32];
    __shared__ __attribute__((aligned(16))) short Bs[128 * 32];

    const int t = threadIdx.x, lane = t & 63, w = t >> 6;
    const int lr = lane & 15, quad = lane >> 4;
    const int m0 = blockIdx.y * 128, n0 = blockIdx.x * 128;
    const int wm = (w >> 1) * 64, wn = (w & 1) * 64;
    const int sr = lane >> 2, sc = lane & 3;

    f4v acc[4][4] = {};

    for (int kb = 0; kb < K; kb += 32) {
#pragma unroll
        for (int p = 0; p < 2; ++p) {
            const int s = 2 * w + p;
            const int r = s * 16 + sr;
            const int g = sc ^ ((r >> 1) & 3);
            glds16(A + (size_t)(m0 + r) * K + kb + g * 8, &As[s * 512]);
            glds16(B + (size_t)(n0 + r) * K + kb + g * 8, &Bs[s * 512]);
        }
        __syncthreads();
        sh8 af[4], bfr[4];
#pragma unroll
        for (int i = 0; i < 4; ++i) {
            const int ra = wm + i * 16 + lr;
            af[i] = *reinterpret_cast<const sh8*>(&As[ra * 32 + ((quad ^ ((ra >> 1) & 3)) << 3)]);
            const int rb = wn + i * 16 + lr;
            bfr[i] = *reinterpret_cast<const sh8*>(&Bs[rb * 32 + ((quad ^ ((rb >> 1) & 3)) << 3)]);
        }
#pragma unroll
        for (int mi = 0; mi < 4; ++mi)
#pragma unroll
            for (int ni = 0; ni < 4; ++ni)
                acc[mi][ni] = __builtin_amdgcn_mfma_f32_16x16x32_bf16(af[mi], bfr[ni], acc[mi][ni], 0, 0, 0);
        __syncthreads();
    }

#pragma unroll
    for (int ni = 0; ni < 4; ++ni) {
        const int col = n0 + wn + ni * 16 + lr;
        const float bv = bias[col];
#pragma unroll
        for (int mi = 0; mi < 4; ++mi) {
            const int row = m0 + wm + mi * 16 + quad * 4;
#pragma unroll
            for (int i = 0; i < 4; ++i)
                Cv[(size_t)(row + i) * N + col] = acc[mi][ni][i] + bv;
        }
    }
}

// ---------------- flash attention: S^T/O^T formulation, P in registers ----------------
// QKb [8192][1280]: Q cols 0..1023 (pre-scaled by 0.125*log2e), K cols 1024..1279.
// Vt [256][8192]: V^T, token-contiguous rows.
// R5 post-mortem: __launch_bounds__(512,4) acted as min-4-BLOCKS/CU (CUDA
// semantics) -> 64-VGPR cap -> ~60MB scratch spill traffic (WRITE_SIZE 16->76MB),
// which sabotaged the 32-q-cols-per-wave retest. R6: identical structure with
// __launch_bounds__(512,2) -> 128-VGPR cap, matching the grid's natural 2
// blocks/CU (512 blocks, 48KB LDS). Expected VGPR ~100-120, no spill.
// Structure recap: 32 q-cols/wave halves per-wave LDS-read traffic vs R2-R4
// (each K/V fragment read feeds 2 q-groups); Ks dbuf + counted vmcnt(2); Vs
// single-buffered staged after release barrier; hoisted base+imm LDS reads;
// l-sum via ones-row MFMA.
__global__ __launch_bounds__(512, 2)
void flash_attn(const short* __restrict__ QKb, const short* __restrict__ Vt,
                short* __restrict__ Og)
{
    constexpr int L = 2048, LQ = 1280, HD = 64;
    constexpr int NT = L / 128;                              // 16 key-tiles of 128
    // layout: Ks0 [0,8192) | Ks1 [8192,16384) | Vs [16384,24576)  (shorts) = 48 KB
    __shared__ __attribute__((aligned(16))) short smem[3 * 8192];

    const int t = threadIdx.x, lane = t & 63, w = t >> 6;    // w = 0..7
    const int lr = lane & 15, quad = lane >> 4;
    const int qt = blockIdx.x, h = blockIdx.y, b = blockIdx.z;
    const int kh = h >> 2;
    const int q0 = qt * 256;                                 // block covers 256 q-cols
    const int kcol = 1024 + kh * HD;

    // Q B-frags (wave owns q-cols q0 + w*32 .. w*32+31 of S^T / O^T)
    sh8 qf[2][2];
#pragma unroll
    for (int nt = 0; nt < 2; ++nt)
#pragma unroll
        for (int ks = 0; ks < 2; ++ks)
            qf[nt][ks] = *reinterpret_cast<const sh8*>(
                QKb + (size_t)(b * L + q0 + w * 32 + nt * 16 + lr) * LQ + h * HD + ks * 32 + quad * 8);

    f4v oT[4][2] = {};
    f4v lacc[2] = {};                                // denominator via MFMA ones-row
    sh8 ones;
#pragma unroll
    for (int i = 0; i < 8; ++i) ones[i] = (short)0x3F80;   // bf16 1.0

    // hoisted LDS read bases: lane-dependent, tile-invariant. All per-tile reads
    // are base + compile-time immediate (Ks: +buf*16KB +(half*4+nl)*2KB; Vs: +m*4KB).
    const int f7 = lr & 7, f15 = lr & 15;
    const short* const Ka0 = &smem[lr * 64 + ((quad ^ f7) << 3)];
    const short* const Ka1 = &smem[lr * 64 + (((4 + quad) ^ f7) << 3)];
    const short* const Vr[4] = {
        &smem[16384 + lr * 128 + (((0  + quad) ^ f15) << 3)],
        &smem[16384 + lr * 128 + (((4  + quad) ^ f15) << 3)],
        &smem[16384 + lr * 128 + (((8  + quad) ^ f15) << 3)],
        &smem[16384 + lr * 128 + (((12 + quad) ^ f15) << 3)] };

    // staging pointers, advanced by fixed stride per tile (no per-tile addr rebuild)
    const int r8 = lane >> 3, g8 = lane & 7;        // K staging: row-in-seg, chunk
    const int v_r4 = lane >> 4, v_g = lane & 15;    // V staging: row-in-seg, chunk
    const short* Vbase = Vt + (size_t)kh * HD * 8192;
    const short* Kp[2];
    const short* Vp[2];
#pragma unroll
    for (int p = 0; p < 2; ++p) {
        const int s = 2 * w + p;
        const int rk = s * 8 + r8;                   // perm-row 0..127
        const int mm = rk & 15;
        const int key = ((rk >> 5) << 5) + ((mm >> 2) << 3) + (((rk >> 4) & 1) << 2) + (mm & 3);
        const int gk = g8 ^ (rk & 7);
        Kp[p] = QKb + (size_t)(b * L + key) * LQ + kcol + gk * 8;
        const int rv = s * 4 + v_r4;                 // d-row 0..63
        const int gv = v_g ^ (rv & 15);
        Vp[p] = Vbase + (size_t)rv * 8192 + b * L + gv * 8;
    }

    // Ks [128 perm-rows][64 d] (swz ^(r&7)), double-buffered; 2 glds16/thread
    auto stageK = [&](int buf) {
#pragma unroll
        for (int p = 0; p < 2; ++p) {
            glds16(Kp[p], &smem[buf * 8192 + (2 * w + p) * 512]);
            Kp[p] += 128 * LQ;                       // next 128 keys (token rows)
        }
    };
    // Vs [64 d][128 keys] (swz ^(r&15)), single-buffered; 2 glds16/thread
    auto stageV = [&]() {
#pragma unroll
        for (int p = 0; p < 2; ++p) {
            glds16(Vp[p], &smem[16384 + (2 * w + p) * 512]);
            Vp[p] += 128;                            // next 128 keys (within V^T row)
        }
    };

    auto body = [&](int buf, int kt) {
        if (kt + 1 < NT) {
            stageK(buf ^ 1);                         // issue next K-tile early
            // outstanding (oldest->newest): K(kt)2, V(kt)2, K(kt+1)2 -> wait cur tile
            asm volatile("s_waitcnt vmcnt(2)" ::: "memory");
        } else {
            asm volatile("s_waitcnt vmcnt(0)" ::: "memory");
        }
        __builtin_amdgcn_s_barrier();                // publish: tile kt (Ks+Vs) ready
        asm volatile("" ::: "memory");

        const int kb = buf * 8192;                   // compile-time after unroll

#pragma unroll
        for (int half = 0; half < 2; ++half) {
            // S^T = K·Q^T for keys [half*64, half*64+64) x 32 q-cols
            f4v st[4][2] = {};
            __builtin_amdgcn_s_setprio(1);
#pragma unroll
            for (int nl = 0; nl < 4; ++nl) {
                sh8 a0 = *reinterpret_cast<const sh8*>(Ka0 + kb + (half * 4 + nl) * 1024);
                sh8 a1 = *reinterpret_cast<const sh8*>(Ka1 + kb + (half * 4 + nl) * 1024);
#pragma unroll
                for (int nt = 0; nt < 2; ++nt) {
                    st[nl][nt] = __builtin_amdgcn_mfma_f32_16x16x32_bf16(a0, qf[nt][0], st[nl][nt], 0, 0, 0);
                    st[nl][nt] = __builtin_amdgcn_mfma_f32_16x16x32_bf16(a1, qf[nt][1], st[nl][nt], 0, 0, 0);
                }
            }
            __builtin_amdgcn_s_setprio(0);

            // exp2 -> P^T B-frags in registers -> PV MFMA (+ l via ones-row MFMA)
            // vf[4] loaded once per cl, reused for BOTH nt -> V LDS traffic halved
#pragma unroll
            for (int cl = 0; cl < 2; ++cl) {
                const int c = half * 2 + cl;
                sh8 vf[4];
#pragma unroll
                for (int m = 0; m < 4; ++m)
                    vf[m] = *reinterpret_cast<const sh8*>(Vr[c] + m * 2048);
#pragma unroll
                for (int nt = 0; nt < 2; ++nt) {
                    f4v e0, e1;
#pragma unroll
                    for (int i = 0; i < 4; ++i) {
                        e0[i] = EXP2(st[2 * cl][nt][i]);
                        e1[i] = EXP2(st[2 * cl + 1][nt][i]);
                    }
                    u4v pu = { pk_bf16(e0[0], e0[1]), pk_bf16(e0[2], e0[3]),
                               pk_bf16(e1[0], e1[1]), pk_bf16(e1[2], e1[3]) };
                    sh8 pf = __builtin_bit_cast(sh8, pu);
                    __builtin_amdgcn_s_setprio(1);
                    lacc[nt] = __builtin_amdgcn_mfma_f32_16x16x32_bf16(ones, pf, lacc[nt], 0, 0, 0);
#pragma unroll
                    for (int m = 0; m < 4; ++m)
                        oT[m][nt] = __builtin_amdgcn_mfma_f32_16x16x32_bf16(vf[m], pf, oT[m][nt], 0, 0, 0);
                    __builtin_amdgcn_s_setprio(0);
                }
            }
        }

        asm volatile("" ::: "memory");               // reads done before release
        __builtin_amdgcn_s_barrier();                // release: Ks[buf^1] + Vs writable
        asm volatile("" ::: "memory");
        if (kt + 1 < NT) stageV();                   // stage V(kt+1) into Vs
    };

    stageK(0);                                       // prologue prefetch
    stageV();
#pragma unroll 1
    for (int kt = 0; kt < NT; kt += 2) {
        body(0, kt);
        body(1, kt + 1);
    }

    // normalize + store O^T -> Og[token][h*64+d].  l = lacc[nt][i] (rows identical).
#pragma unroll
    for (int nt = 0; nt < 2; ++nt) {
        const float inv = 1.0f / lacc[nt][0];
        const size_t tok = (size_t)b * L + q0 + w * 32 + nt * 16 + lr;
        short* op = Og + tok * 1024 + h * HD + quad * 4;
#pragma unroll
        for (int m = 0; m < 4; ++m) {
            u2v pk2 = { pk_bf16(oT[m][nt][0] * inv, oT[m][nt][1] * inv),
                        pk_bf16(oT[m][nt][2] * inv, oT[m][nt][3] * inv) };
            *reinterpret_cast<u2v*>(op + m * 16) = pk2;
        }
    }
}

extern "C" void kernel_launch(void* const* d_in, const int* in_sizes, int n_in,
                              void* d_out, int out_size, void* d_ws, size_t ws_size,
                              hipStream_t stream)
{
    (void)in_sizes; (void)n_in; (void)out_size; (void)ws_size;
    const float* x  = (const float*)d_in[0];
    const float* Wq = (const float*)d_in[1];
    const float* bq = (const float*)d_in[2];
    const float* Wk = (const float*)d_in[3];
    const float* bk = (const float*)d_in[4];
    const float* Wv = (const float*)d_in[5];
    const float* bv = (const float*)d_in[6];
    const float* Wo = (const float*)d_in[7];
    const float* bo = (const float*)d_in[8];
    float* out = (float*)d_out;

    char* ws = (char*)d_ws;
    short* xb   = (short*)(ws);                     // 8192x1024 bf16 = 16 MB
    short* Ob   = (short*)(ws);                     // aliases xb (dead after proj)
    short* Wqkb = (short*)(ws + 16777216);          // 1280x1024 bf16 = 2.5 MB
    short* Wvb  = (short*)(ws + 19398656);          // 256x1024 bf16 = 512 KB
    short* Wob  = (short*)(ws + 19922944);          // 1024x1024 bf16 = 2 MB
    float* bqk  = (float*)(ws + 22020096);          // 1280 fp32
    float* bvf  = (float*)(ws + 22025216);          // 256 fp32
    short* Vt   = (short*)(ws + 25165824);          // 256x8192 bf16 = 4 MB (V^T)
    short* QKb  = (short*)d_out;                    // 8192x1280 bf16 = 20 MB scratch

    pack_all<<<10754, 256, 0, stream>>>(x, Wq, Wk, Wv, Wo, bq, bk, bv,
                                        xb, Wqkb, Wvb, Wob, bqk, bvf);
    proj_fused<<<768, 256, 0, stream>>>(xb, Wqkb, bqk, QKb, Wvb, bvf, Vt);
    flash_attn<<<dim3(8, 16, 4), 512, 0, stream>>>(QKb, Vt, Ob);
    gemm_out<<<dim3(8, 64), 256, 0, stream>>>(Ob, Wob, bo, out, 8192, 1024, 1024);
}

// Round 7
// 253.662 us; speedup vs baseline: 1.0420x; 1.0055x over previous
//
#include <hip/hip_runtime.h>
#include <hip/hip_bf16.h>

typedef __attribute__((ext_vector_type(8))) short sh8;
typedef __attribute__((ext_vector_type(4))) short sh4;
typedef __attribute__((ext_vector_type(4))) float f4v;
typedef __attribute__((ext_vector_type(4))) unsigned u4v;
typedef __attribute__((ext_vector_type(2))) unsigned u2v;

#define SCALE_Q 0.1803368801f   // 0.125 * log2(e): folds softmax scale AND exp->exp2

__device__ __forceinline__ short f2bf(float f) {
    unsigned u = __builtin_bit_cast(unsigned, f);
    u += 0x7fffu + ((u >> 16) & 1u);   // RNE
    return (short)(u >> 16);
}

#if __has_builtin(__builtin_amdgcn_cvt_pk_bf16_f32)
__device__ __forceinline__ unsigned pk_bf16(float a, float b) {
    return __builtin_bit_cast(unsigned, __builtin_amdgcn_cvt_pk_bf16_f32(a, b));
}
#else
__device__ __forceinline__ unsigned pk_bf16(float a, float b) {
    return (unsigned)(unsigned short)f2bf(a) | ((unsigned)(unsigned short)f2bf(b) << 16);
}
#endif

#if __has_builtin(__builtin_amdgcn_exp2f)
#define EXP2(x) __builtin_amdgcn_exp2f(x)
#else
#define EXP2(x) exp2f(x)
#endif

__device__ __forceinline__ void glds16(const short* g, short* l) {
    __builtin_amdgcn_global_load_lds(
        (const __attribute__((address_space(1))) void*)g,
        (__attribute__((address_space(3))) void*)l, 16, 0, 0);
}

// ---------------- pack: fp32 -> bf16 conversions + weight fusion ----------------
// vec4 regions: x->xb | Wq->Wqkb(scaled) | Wk->Wqkb+1M | Wv->Wvb | Wo->Wob | biases
__global__ __launch_bounds__(256)
void pack_all(const float* __restrict__ x,  const float* __restrict__ Wq,
              const float* __restrict__ Wk, const float* __restrict__ Wv,
              const float* __restrict__ Wo, const float* __restrict__ bq,
              const float* __restrict__ bk, const float* __restrict__ bv,
              short* __restrict__ xb, short* __restrict__ Wqkb,
              short* __restrict__ Wvb, short* __restrict__ Wob,
              float* __restrict__ bqk, float* __restrict__ bvf)
{
    const long idx = (long)blockIdx.x * 256 + threadIdx.x;
    if (idx >= 2752896) return;
    const float* src; short* dst; float sc = 1.0f; long off;
    if (idx < 2097152)       { off = idx;           src = x;  dst = xb; }
    else if (idx < 2359296)  { off = idx - 2097152; src = Wq; dst = Wqkb;           sc = SCALE_Q; }
    else if (idx < 2424832)  { off = idx - 2359296; src = Wk; dst = Wqkb + 1048576; }
    else if (idx < 2490368)  { off = idx - 2424832; src = Wv; dst = Wvb; }
    else if (idx < 2752512)  { off = idx - 2490368; src = Wo; dst = Wob; }
    else {
        long j = idx - 2752512;  // 0..383
        const float* bs; float* bd; float s2 = 1.0f;
        if (j < 256)      { bs = bq + j * 4;         bd = bqk + j * 4;          s2 = SCALE_Q; }
        else if (j < 320) { bs = bk + (j - 256) * 4; bd = bqk + 1024 + (j - 256) * 4; }
        else              { bs = bv + (j - 320) * 4; bd = bvf + (j - 320) * 4; }
        f4v v = *reinterpret_cast<const f4v*>(bs);
        f4v o = { v[0] * s2, v[1] * s2, v[2] * s2, v[3] * s2 };
        *reinterpret_cast<f4v*>(bd) = o;
        return;
    }
    f4v v = *reinterpret_cast<const f4v*>(src + off * 4);
    sh4 o; o[0] = f2bf(v[0] * sc); o[1] = f2bf(v[1] * sc);
    o[2] = f2bf(v[2] * sc); o[3] = f2bf(v[3] * sc);
    *reinterpret_cast<sh4*>(dst + off * 4) = o;
}

// ---------------- fused projection: QK GEMM + V-transposed GEMM, one grid ----------------
// Blocks 0..639:   QKb[8192][1280] = xb[8192][1024] · Wqkb[1280][1024]^T + bqk (col bias)
// Blocks 640..767: Vt [256][8192]  = Wvb[256][1024] · xb[8192][1024]^T  + bvf (row bias)
//   (swapped operands make the token axis the store-lane axis -> coalesced Vt, no scatter)
// Grid 768 = 3 x 256: zero tail. K=1024, 128x128 tiles, m97-style glds staging.
__global__ __launch_bounds__(256)
void proj_fused(const short* __restrict__ xb, const short* __restrict__ Wqkb,
                const float* __restrict__ bqk, short* __restrict__ QKb,
                const short* __restrict__ Wvb, const float* __restrict__ bvf,
                short* __restrict__ Vt)
{
    constexpr int K = 1024;
    __shared__ __attribute__((aligned(16))) short As[128 * 32];
    __shared__ __attribute__((aligned(16))) short Bs[128 * 32];

    const int t = threadIdx.x, lane = t & 63, w = t >> 6;
    const int lr = lane & 15, quad = lane >> 4;
    const int wm = (w >> 1) * 64, wn = (w & 1) * 64;
    const int sr = lane >> 2, sc = lane & 3;

    const int id = blockIdx.x;
    const short *A, *B; const float* bias; short* C;
    int m0, n0, N; bool brow;
    if (id < 640) {
        A = xb;  B = Wqkb; bias = bqk; C = QKb; N = 1280;
        m0 = (id / 10) * 128; n0 = (id % 10) * 128; brow = false;
    } else {
        const int v = id - 640;
        A = Wvb; B = xb;   bias = bvf; C = Vt;  N = 8192;
        m0 = (v >> 6) * 128; n0 = (v & 63) * 128; brow = true;
    }

    f4v acc[4][4] = {};

    for (int kb = 0; kb < K; kb += 32) {
#pragma unroll
        for (int p = 0; p < 2; ++p) {
            const int s = 2 * w + p;
            const int r = s * 16 + sr;
            const int g = sc ^ ((r >> 1) & 3);
            glds16(A + (size_t)(m0 + r) * K + kb + g * 8, &As[s * 512]);
            glds16(B + (size_t)(n0 + r) * K + kb + g * 8, &Bs[s * 512]);
        }
        __syncthreads();
        sh8 af[4], bfr[4];
#pragma unroll
        for (int i = 0; i < 4; ++i) {
            const int ra = wm + i * 16 + lr;
            af[i] = *reinterpret_cast<const sh8*>(&As[ra * 32 + ((quad ^ ((ra >> 1) & 3)) << 3)]);
            const int rb = wn + i * 16 + lr;
            bfr[i] = *reinterpret_cast<const sh8*>(&Bs[rb * 32 + ((quad ^ ((rb >> 1) & 3)) << 3)]);
        }
#pragma unroll
        for (int mi = 0; mi < 4; ++mi)
#pragma unroll
            for (int ni = 0; ni < 4; ++ni)
                acc[mi][ni] = __builtin_amdgcn_mfma_f32_16x16x32_bf16(af[mi], bfr[ni], acc[mi][ni], 0, 0, 0);
        __syncthreads();
    }

#pragma unroll
    for (int mi = 0; mi < 4; ++mi) {
        const int row = m0 + wm + mi * 16 + quad * 4;
        f4v br4 = {};
        if (brow) br4 = *reinterpret_cast<const f4v*>(&bias[row]);
#pragma unroll
        for (int ni = 0; ni < 4; ++ni) {
            const int col = n0 + wn + ni * 16 + lr;
            const float bc = brow ? 0.f : bias[col];
#pragma unroll
            for (int i = 0; i < 4; ++i) {
                const float v = acc[mi][ni][i] + (brow ? br4[i] : bc);
                C[(size_t)(row + i) * N + col] = f2bf(v);
            }
        }
    }
}

// ---------------- O-projection GEMM: out[M,N] = A[M,K] · W[N,K]^T + bias (fp32 out) ----------------
__global__ __launch_bounds__(256)
void gemm_out(const short* __restrict__ A, const short* __restrict__ B,
              const float* __restrict__ bias, float* __restrict__ Cv,
              int M, int N, int K)
{
    __shared__ __attribute__((aligned(16))) short As[128 * 32];
    __shared__ __attribute__((aligned(16))) short Bs[128 * 32];

    const int t = threadIdx.x, lane = t & 63, w = t >> 6;
    const int lr = lane & 15, quad = lane >> 4;
    const int m0 = blockIdx.y * 128, n0 = blockIdx.x * 128;
    const int wm = (w >> 1) * 64, wn = (w & 1) * 64;
    const int sr = lane >> 2, sc = lane & 3;

    f4v acc[4][4] = {};

    for (int kb = 0; kb < K; kb += 32) {
#pragma unroll
        for (int p = 0; p < 2; ++p) {
            const int s = 2 * w + p;
            const int r = s * 16 + sr;
            const int g = sc ^ ((r >> 1) & 3);
            glds16(A + (size_t)(m0 + r) * K + kb + g * 8, &As[s * 512]);
            glds16(B + (size_t)(n0 + r) * K + kb + g * 8, &Bs[s * 512]);
        }
        __syncthreads();
        sh8 af[4], bfr[4];
#pragma unroll
        for (int i = 0; i < 4; ++i) {
            const int ra = wm + i * 16 + lr;
            af[i] = *reinterpret_cast<const sh8*>(&As[ra * 32 + ((quad ^ ((ra >> 1) & 3)) << 3)]);
            const int rb = wn + i * 16 + lr;
            bfr[i] = *reinterpret_cast<const sh8*>(&Bs[rb * 32 + ((quad ^ ((rb >> 1) & 3)) << 3)]);
        }
#pragma unroll
        for (int mi = 0; mi < 4; ++mi)
#pragma unroll
            for (int ni = 0; ni < 4; ++ni)
                acc[mi][ni] = __builtin_amdgcn_mfma_f32_16x16x32_bf16(af[mi], bfr[ni], acc[mi][ni], 0, 0, 0);
        __syncthreads();
    }

#pragma unroll
    for (int ni = 0; ni < 4; ++ni) {
        const int col = n0 + wn + ni * 16 + lr;
        const float bv = bias[col];
#pragma unroll
        for (int mi = 0; mi < 4; ++mi) {
            const int row = m0 + wm + mi * 16 + quad * 4;
#pragma unroll
            for (int i = 0; i < 4; ++i)
                Cv[(size_t)(row + i) * N + col] = acc[mi][ni][i] + bv;
        }
    }
}

// ---------------- flash attention: S^T/O^T formulation, P in registers ----------------
// QKb [8192][1280]: Q cols 0..1023 (pre-scaled by 0.125*log2e), K cols 1024..1279.
// Vt [256][8192]: V^T, token-contiguous rows.
// R6 post-mortem: halving LDS traffic (32q/wave) did NOT help -> kernel is
// phase-lockstep latency-bound, not LDS-BW-bound. R7 = R3-exact config (best
// measured, 92.5us: 128-key tiles, 16q/wave, K+V both dbuf, 64KB, 1024 blocks,
// no launch-bounds min) + two additive changes:
//  (1) hoisted base+immediate LDS reads (R4-proven component),
//  (2) T15 deferred last chunk: c3's V-frags (vfD) + S^T regs (stD) held across
//      the release barrier; its exp2+pack+PV executes at the TOP of the next
//      tile, overlapping the barrier edge + next tile's ds_read latency with
//      register-only work. lgkmcnt(0) before the release barrier makes the held
//      frags race-free vs next staging writes.
__global__ __launch_bounds__(512)
void flash_attn(const short* __restrict__ QKb, const short* __restrict__ Vt,
                short* __restrict__ Og)
{
    constexpr int L = 2048, LQ = 1280, HD = 64;
    constexpr int NT = L / 128;                              // 16 key-tiles of 128
    // layout per buf: Ks [128 perm-rows][64 d] (8192 sh) | Vs [64 d][128 keys] (8192 sh)
    __shared__ __attribute__((aligned(16))) short smem[2 * 16384]; // 64 KB

    const int t = threadIdx.x, lane = t & 63, w = t >> 6;    // w = 0..7
    const int lr = lane & 15, quad = lane >> 4;
    const int qt = blockIdx.x, h = blockIdx.y, b = blockIdx.z;
    const int kh = h >> 2;
    const int q0 = qt * 128;
    const int kcol = 1024 + kh * HD;

    // Q B-frags (wave owns q-cols w*16..w*16+15 of S^T / O^T)
    sh8 qf[2];
#pragma unroll
    for (int ks = 0; ks < 2; ++ks)
        qf[ks] = *reinterpret_cast<const sh8*>(
            QKb + (size_t)(b * L + q0 + w * 16 + lr) * LQ + h * HD + ks * 32 + quad * 8);

    f4v oT[4] = {};
    f4v lacc = {};                                   // denominator via MFMA ones-row
    sh8 ones;
#pragma unroll
    for (int i = 0; i < 8; ++i) ones[i] = (short)0x3F80;   // bf16 1.0

    // hoisted LDS read bases: lane-dependent, tile-invariant. Per-tile reads are
    // base + compile-time imm (Ks: +buf*16384 + (half*4+nl)*1024; Vs: +8192 + m*2048).
    const int f7 = lr & 7, f15 = lr & 15;
    const short* const Ka0 = &smem[lr * 64 + ((quad ^ f7) << 3)];
    const short* const Ka1 = &smem[lr * 64 + (((4 + quad) ^ f7) << 3)];
    const short* const Vr[4] = {
        &smem[8192 + lr * 128 + (((0  + quad) ^ f15) << 3)],
        &smem[8192 + lr * 128 + (((4  + quad) ^ f15) << 3)],
        &smem[8192 + lr * 128 + (((8  + quad) ^ f15) << 3)],
        &smem[8192 + lr * 128 + (((12 + quad) ^ f15) << 3)] };

    // staging pointers, advanced by fixed stride per tile
    const int r8 = lane >> 3, g8 = lane & 7;        // K staging: row-in-seg, chunk
    const int v_r4 = lane >> 4, v_g = lane & 15;    // V staging: row-in-seg, chunk
    const short* Vbase = Vt + (size_t)kh * HD * 8192;
    const short* Kp[2];
    const short* Vp[2];
#pragma unroll
    for (int p = 0; p < 2; ++p) {
        const int s = 2 * w + p;
        const int rk = s * 8 + r8;                   // perm-row 0..127
        const int mm = rk & 15;
        const int key = ((rk >> 5) << 5) + ((mm >> 2) << 3) + (((rk >> 4) & 1) << 2) + (mm & 3);
        const int gk = g8 ^ (rk & 7);
        Kp[p] = QKb + (size_t)(b * L + key) * LQ + kcol + gk * 8;
        const int rv = s * 4 + v_r4;                 // d-row 0..63
        const int gv = v_g ^ (rv & 15);
        Vp[p] = Vbase + (size_t)rv * 8192 + b * L + gv * 8;
    }

    // stage one 128-key tile (K + V) into buf; 4 glds16 per thread per tile
    auto stage = [&](int buf) {
        short* Ks = smem + buf * 16384;
        short* Vs = Ks + 8192;
#pragma unroll
        for (int p = 0; p < 2; ++p) {
            glds16(Kp[p], &Ks[(2 * w + p) * 512]);
            Kp[p] += 128 * LQ;                       // next 128 keys (token rows)
            glds16(Vp[p], &Vs[(2 * w + p) * 512]);
            Vp[p] += 128;                            // next 128 keys (within V^T row)
        }
    };

    // deferred-chunk state (tile kt's c3, executed at top of tile kt+1)
    f4v stD0, stD1;
    sh8 vfD[4];

    // softmax+PV for one 32-key chunk (register-only given s0,s1,vf)
    auto smpv = [&](const f4v& s0, const f4v& s1, const sh8* vf) {
        f4v e0, e1;
#pragma unroll
        for (int i = 0; i < 4; ++i) {
            e0[i] = EXP2(s0[i]);
            e1[i] = EXP2(s1[i]);
        }
        u4v pu = { pk_bf16(e0[0], e0[1]), pk_bf16(e0[2], e0[3]),
                   pk_bf16(e1[0], e1[1]), pk_bf16(e1[2], e1[3]) };
        sh8 pf = __builtin_bit_cast(sh8, pu);
        __builtin_amdgcn_s_setprio(1);
        lacc = __builtin_amdgcn_mfma_f32_16x16x32_bf16(ones, pf, lacc, 0, 0, 0);
#pragma unroll
        for (int m = 0; m < 4; ++m)
            oT[m] = __builtin_amdgcn_mfma_f32_16x16x32_bf16(vf[m], pf, oT[m], 0, 0, 0);
        __builtin_amdgcn_s_setprio(0);
    };

    auto body = [&](int buf, int kt) {
        if (kt + 1 < NT) {
            stage(buf ^ 1);                          // issue next tile early
            // outstanding: cur tile 4 + next tile 4 -> wait until cur landed
            asm volatile("s_waitcnt vmcnt(4)" ::: "memory");
        } else {
            asm volatile("s_waitcnt vmcnt(0)" ::: "memory");
        }
        __builtin_amdgcn_s_barrier();                // publish: tile kt ready
        asm volatile("" ::: "memory");

        const int kb = buf * 16384;                  // compile-time after unroll

        // deferred c3 of previous tile: register-only, overlaps this tile's
        // ds_read latency + barrier edge
        if (kt) smpv(stD0, stD1, vfD);

        // S^T = K·Q^T, both halves (16 MFMA)
        f4v stA[4] = {}, stB[4] = {};
        __builtin_amdgcn_s_setprio(1);
#pragma unroll
        for (int nl = 0; nl < 4; ++nl) {
            sh8 a0 = *reinterpret_cast<const sh8*>(Ka0 + kb + nl * 1024);
            sh8 a1 = *reinterpret_cast<const sh8*>(Ka1 + kb + nl * 1024);
            stA[nl] = __builtin_amdgcn_mfma_f32_16x16x32_bf16(a0, qf[0], stA[nl], 0, 0, 0);
            stA[nl] = __builtin_amdgcn_mfma_f32_16x16x32_bf16(a1, qf[1], stA[nl], 0, 0, 0);
        }
#pragma unroll
        for (int nl = 0; nl < 4; ++nl) {
            sh8 a0 = *reinterpret_cast<const sh8*>(Ka0 + kb + (4 + nl) * 1024);
            sh8 a1 = *reinterpret_cast<const sh8*>(Ka1 + kb + (4 + nl) * 1024);
            stB[nl] = __builtin_amdgcn_mfma_f32_16x16x32_bf16(a0, qf[0], stB[nl], 0, 0, 0);
            stB[nl] = __builtin_amdgcn_mfma_f32_16x16x32_bf16(a1, qf[1], stB[nl], 0, 0, 0);
        }
        __builtin_amdgcn_s_setprio(0);

        // chunks c0..c2 in place
        {
            sh8 vf[4];
#pragma unroll
            for (int m = 0; m < 4; ++m) vf[m] = *reinterpret_cast<const sh8*>(Vr[0] + kb + m * 2048);
            smpv(stA[0], stA[1], vf);
#pragma unroll
            for (int m = 0; m < 4; ++m) vf[m] = *reinterpret_cast<const sh8*>(Vr[1] + kb + m * 2048);
            smpv(stA[2], stA[3], vf);
#pragma unroll
            for (int m = 0; m < 4; ++m) vf[m] = *reinterpret_cast<const sh8*>(Vr[2] + kb + m * 2048);
            smpv(stB[0], stB[1], vf);
        }

        // save c3 for deferred execution
#pragma unroll
        for (int m = 0; m < 4; ++m)
            vfD[m] = *reinterpret_cast<const sh8*>(Vr[3] + kb + m * 2048);
        stD0 = stB[2]; stD1 = stB[3];

        asm volatile("s_waitcnt lgkmcnt(0)" ::: "memory");  // vfD + all reads landed
        __builtin_amdgcn_s_barrier();                // release: buf may be restaged
        asm volatile("" ::: "memory");
    };

    stage(0);                                        // prologue prefetch
#pragma unroll 1
    for (int kt = 0; kt < NT; kt += 2) {
        body(0, kt);
        body(1, kt + 1);
    }
    smpv(stD0, stD1, vfD);                           // final deferred chunk

    // normalize + store O^T -> Og[token][h*64+d].  l = lacc[i] (rows identical).
    {
        const float inv = 1.0f / lacc[0];
        const size_t tok = (size_t)b * L + q0 + w * 16 + lr;
        short* op = Og + tok * 1024 + h * HD + quad * 4;
#pragma unroll
        for (int m = 0; m < 4; ++m) {
            u2v pk2 = { pk_bf16(oT[m][0] * inv, oT[m][1] * inv),
                        pk_bf16(oT[m][2] * inv, oT[m][3] * inv) };
            *reinterpret_cast<u2v*>(op + m * 16) = pk2;
        }
    }
}

extern "C" void kernel_launch(void* const* d_in, const int* in_sizes, int n_in,
                              void* d_out, int out_size, void* d_ws, size_t ws_size,
                              hipStream_t stream)
{
    (void)in_sizes; (void)n_in; (void)out_size; (void)ws_size;
    const float* x  = (const float*)d_in[0];
    const float* Wq = (const float*)d_in[1];
    const float* bq = (const float*)d_in[2];
    const float* Wk = (const float*)d_in[3];
    const float* bk = (const float*)d_in[4];
    const float* Wv = (const float*)d_in[5];
    const float* bv = (const float*)d_in[6];
    const float* Wo = (const float*)d_in[7];
    const float* bo = (const float*)d_in[8];
    float* out = (float*)d_out;

    char* ws = (char*)d_ws;
    short* xb   = (short*)(ws);                     // 8192x1024 bf16 = 16 MB
    short* Ob   = (short*)(ws);                     // aliases xb (dead after proj)
    short* Wqkb = (short*)(ws + 16777216);          // 1280x1024 bf16 = 2.5 MB
    short* Wvb  = (short*)(ws + 19398656);          // 256x1024 bf16 = 512 KB
    short* Wob  = (short*)(ws + 19922944);          // 1024x1024 bf16 = 2 MB
    float* bqk  = (float*)(ws + 22020096);          // 1280 fp32
    float* bvf  = (float*)(ws + 22025216);          // 256 fp32
    short* Vt   = (short*)(ws + 25165824);          // 256x8192 bf16 = 4 MB (V^T)
    short* QKb  = (short*)d_out;                    // 8192x1280 bf16 = 20 MB scratch

    pack_all<<<10754, 256, 0, stream>>>(x, Wq, Wk, Wv, Wo, bq, bk, bv,
                                        xb, Wqkb, Wvb, Wob, bqk, bvf);
    proj_fused<<<768, 256, 0, stream>>>(xb, Wqkb, bqk, QKb, Wvb, bvf, Vt);
    flash_attn<<<dim3(16, 16, 4), 512, 0, stream>>>(QKb, Vt, Ob);
    gemm_out<<<dim3(8, 64), 256, 0, stream>>>(Ob, Wob, bo, out, 8192, 1024, 1024);
}

// Round 10
// 246.557 us; speedup vs baseline: 1.0720x; 1.0288x over previous
//
#include <hip/hip_runtime.h>
#include <hip/hip_bf16.h>

typedef __attribute__((ext_vector_type(8))) short sh8;
typedef __attribute__((ext_vector_type(4))) short sh4;
typedef __attribute__((ext_vector_type(4))) float f4v;
typedef __attribute__((ext_vector_type(4))) unsigned u4v;
typedef __attribute__((ext_vector_type(2))) unsigned u2v;

#define SCALE_Q 0.1803368801f   // 0.125 * log2(e): folds softmax scale AND exp->exp2

__device__ __forceinline__ short f2bf(float f) {
    unsigned u = __builtin_bit_cast(unsigned, f);
    u += 0x7fffu + ((u >> 16) & 1u);   // RNE
    return (short)(u >> 16);
}

// manual RNE pack (lo=a, hi=b) — used for the Og store (full RNE, R8/R9 lesson)
__device__ __forceinline__ unsigned pk_bf16(float a, float b) {
    return (unsigned)(unsigned short)f2bf(a) | ((unsigned)(unsigned short)f2bf(b) << 16);
}

// gfx950 v_cvt_pk_bf16_f32 TRUNCATES (RTZ; R8/R9 empirical). Pre-biasing the
// float bits by +0x8000 turns trunc into round-half-up (== RNE except exact
// ties, <=0.5 ulp, unbiased). 3 VALU per pair vs ~10 manual. P>=0, no sign edge.
__device__ __forceinline__ unsigned cvtpk_rhu(float a, float b) {
    float fa = __builtin_bit_cast(float, __builtin_bit_cast(unsigned, a) + 0x8000u);
    float fb = __builtin_bit_cast(float, __builtin_bit_cast(unsigned, b) + 0x8000u);
    unsigned r;
    asm("v_cvt_pk_bf16_f32 %0, %1, %2" : "=v"(r) : "v"(fa), "v"(fb));
    return r;
}

#if __has_builtin(__builtin_amdgcn_exp2f)
#define EXP2(x) __builtin_amdgcn_exp2f(x)
#else
#define EXP2(x) exp2f(x)
#endif

__device__ __forceinline__ void glds16(const short* g, short* l) {
    __builtin_amdgcn_global_load_lds(
        (const __attribute__((address_space(1))) void*)g,
        (__attribute__((address_space(3))) void*)l, 16, 0, 0);
}

// ---------------- pack: fp32 -> bf16 conversions + weight fusion ----------------
// vec4 regions: x->xb | Wq->Wqkb(scaled) | Wk->Wqkb+1M | Wv->Wvb | Wo->Wob | biases
__global__ __launch_bounds__(256)
void pack_all(const float* __restrict__ x,  const float* __restrict__ Wq,
              const float* __restrict__ Wk, const float* __restrict__ Wv,
              const float* __restrict__ Wo, const float* __restrict__ bq,
              const float* __restrict__ bk, const float* __restrict__ bv,
              short* __restrict__ xb, short* __restrict__ Wqkb,
              short* __restrict__ Wvb, short* __restrict__ Wob,
              float* __restrict__ bqk, float* __restrict__ bvf)
{
    const long idx = (long)blockIdx.x * 256 + threadIdx.x;
    if (idx >= 2752896) return;
    const float* src; short* dst; float sc = 1.0f; long off;
    if (idx < 2097152)       { off = idx;           src = x;  dst = xb; }
    else if (idx < 2359296)  { off = idx - 2097152; src = Wq; dst = Wqkb;           sc = SCALE_Q; }
    else if (idx < 2424832)  { off = idx - 2359296; src = Wk; dst = Wqkb + 1048576; }
    else if (idx < 2490368)  { off = idx - 2424832; src = Wv; dst = Wvb; }
    else if (idx < 2752512)  { off = idx - 2490368; src = Wo; dst = Wob; }
    else {
        long j = idx - 2752512;  // 0..383
        const float* bs; float* bd; float s2 = 1.0f;
        if (j < 256)      { bs = bq + j * 4;         bd = bqk + j * 4;          s2 = SCALE_Q; }
        else if (j < 320) { bs = bk + (j - 256) * 4; bd = bqk + 1024 + (j - 256) * 4; }
        else              { bs = bv + (j - 320) * 4; bd = bvf + (j - 320) * 4; }
        f4v v = *reinterpret_cast<const f4v*>(bs);
        f4v o = { v[0] * s2, v[1] * s2, v[2] * s2, v[3] * s2 };
        *reinterpret_cast<f4v*>(bd) = o;
        return;
    }
    f4v v = *reinterpret_cast<const f4v*>(src + off * 4);
    sh4 o; o[0] = f2bf(v[0] * sc); o[1] = f2bf(v[1] * sc);
    o[2] = f2bf(v[2] * sc); o[3] = f2bf(v[3] * sc);
    *reinterpret_cast<sh4*>(dst + off * 4) = o;
}

// ---------------- fused projection: QK GEMM + V-transposed GEMM, one grid ----------------
// Blocks 0..639:   QKb[8192][1280] = xb[8192][1024] · Wqkb[1280][1024]^T + bqk (col bias)
// Blocks 640..767: Vt [256][8192]  = Wvb[256][1024] · xb[8192][1024]^T  + bvf (row bias)
//   (swapped operands make the token axis the store-lane axis -> coalesced Vt, no scatter)
// Grid 768 = 3 x 256: zero tail. K=1024, 128x128 tiles, m97-style glds staging.
__global__ __launch_bounds__(256)
void proj_fused(const short* __restrict__ xb, const short* __restrict__ Wqkb,
                const float* __restrict__ bqk, short* __restrict__ QKb,
                const short* __restrict__ Wvb, const float* __restrict__ bvf,
                short* __restrict__ Vt)
{
    constexpr int K = 1024;
    __shared__ __attribute__((aligned(16))) short As[128 * 32];
    __shared__ __attribute__((aligned(16))) short Bs[128 * 32];

    const int t = threadIdx.x, lane = t & 63, w = t >> 6;
    const int lr = lane & 15, quad = lane >> 4;
    const int wm = (w >> 1) * 64, wn = (w & 1) * 64;
    const int sr = lane >> 2, sc = lane & 3;

    const int id = blockIdx.x;
    const short *A, *B; const float* bias; short* C;
    int m0, n0, N; bool brow;
    if (id < 640) {
        A = xb;  B = Wqkb; bias = bqk; C = QKb; N = 1280;
        m0 = (id / 10) * 128; n0 = (id % 10) * 128; brow = false;
    } else {
        const int v = id - 640;
        A = Wvb; B = xb;   bias = bvf; C = Vt;  N = 8192;
        m0 = (v >> 6) * 128; n0 = (v & 63) * 128; brow = true;
    }

    f4v acc[4][4] = {};

    for (int kb = 0; kb < K; kb += 32) {
#pragma unroll
        for (int p = 0; p < 2; ++p) {
            const int s = 2 * w + p;
            const int r = s * 16 + sr;
            const int g = sc ^ ((r >> 1) & 3);
            glds16(A + (size_t)(m0 + r) * K + kb + g * 8, &As[s * 512]);
            glds16(B + (size_t)(n0 + r) * K + kb + g * 8, &Bs[s * 512]);
        }
        __syncthreads();
        sh8 af[4], bfr[4];
#pragma unroll
        for (int i = 0; i < 4; ++i) {
            const int ra = wm + i * 16 + lr;
            af[i] = *reinterpret_cast<const sh8*>(&As[ra * 32 + ((quad ^ ((ra >> 1) & 3)) << 3)]);
            const int rb = wn + i * 16 + lr;
            bfr[i] = *reinterpret_cast<const sh8*>(&Bs[rb * 32 + ((quad ^ ((rb >> 1) & 3)) << 3)]);
        }
#pragma unroll
        for (int mi = 0; mi < 4; ++mi)
#pragma unroll
            for (int ni = 0; ni < 4; ++ni)
                acc[mi][ni] = __builtin_amdgcn_mfma_f32_16x16x32_bf16(af[mi], bfr[ni], acc[mi][ni], 0, 0, 0);
        __syncthreads();
    }

#pragma unroll
    for (int mi = 0; mi < 4; ++mi) {
        const int row = m0 + wm + mi * 16 + quad * 4;
        f4v br4 = {};
        if (brow) br4 = *reinterpret_cast<const f4v*>(&bias[row]);
#pragma unroll
        for (int ni = 0; ni < 4; ++ni) {
            const int col = n0 + wn + ni * 16 + lr;
            const float bc = brow ? 0.f : bias[col];
#pragma unroll
            for (int i = 0; i < 4; ++i) {
                const float v = acc[mi][ni][i] + (brow ? br4[i] : bc);
                C[(size_t)(row + i) * N + col] = f2bf(v);
            }
        }
    }
}

// ---------------- O-projection GEMM: out[M,N] = A[M,K] · W[N,K]^T + bias (fp32 out) ----------------
__global__ __launch_bounds__(256)
void gemm_out(const short* __restrict__ A, const short* __restrict__ B,
              const float* __restrict__ bias, float* __restrict__ Cv,
              int M, int N, int K)
{
    __shared__ __attribute__((aligned(16))) short As[128 * 32];
    __shared__ __attribute__((aligned(16))) short Bs[128 * 32];

    const int t = threadIdx.x, lane = t & 63, w = t >> 6;
    const int lr = lane & 15, quad = lane >> 4;
    const int m0 = blockIdx.y * 128, n0 = blockIdx.x * 128;
    const int wm = (w >> 1) * 64, wn = (w & 1) * 64;
    const int sr = lane >> 2, sc = lane & 3;

    f4v acc[4][4] = {};

    for (int kb = 0; kb < K; kb += 32) {
#pragma unroll
        for (int p = 0; p < 2; ++p) {
            const int s = 2 * w + p;
            const int r = s * 16 + sr;
            const int g = sc ^ ((r >> 1) & 3);
            glds16(A + (size_t)(m0 + r) * K + kb + g * 8, &As[s * 512]);
            glds16(B + (size_t)(n0 + r) * K + kb + g * 8, &Bs[s * 512]);
        }
        __syncthreads();
        sh8 af[4], bfr[4];
#pragma unroll
        for (int i = 0; i < 4; ++i) {
            const int ra = wm + i * 16 + lr;
            af[i] = *reinterpret_cast<const sh8*>(&As[ra * 32 + ((quad ^ ((ra >> 1) & 3)) << 3)]);
            const int rb = wn + i * 16 + lr;
            bfr[i] = *reinterpret_cast<const sh8*>(&Bs[rb * 32 + ((quad ^ ((rb >> 1) & 3)) << 3)]);
        }
#pragma unroll
        for (int mi = 0; mi < 4; ++mi)
#pragma unroll
            for (int ni = 0; ni < 4; ++ni)
                acc[mi][ni] = __builtin_amdgcn_mfma_f32_16x16x32_bf16(af[mi], bfr[ni], acc[mi][ni], 0, 0, 0);
        __syncthreads();
    }

#pragma unroll
    for (int ni = 0; ni < 4; ++ni) {
        const int col = n0 + wn + ni * 16 + lr;
        const float bv = bias[col];
#pragma unroll
        for (int mi = 0; mi < 4; ++mi) {
            const int row = m0 + wm + mi * 16 + quad * 4;
#pragma unroll
            for (int i = 0; i < 4; ++i)
                Cv[(size_t)(row + i) * N + col] = acc[mi][ni][i] + bv;
        }
    }
}

// ---------------- flash attention: S^T/O^T formulation, P in registers ----------------
// QKb [8192][1280]: Q cols 0..1023 (pre-scaled by 0.125*log2e), K cols 1024..1279.
// Vt [256][8192]: V^T, token-contiguous rows.
// R9 post-mortem: P-pack truncation was the DOMINANT error (3.3e-3 of 3.78e-3);
// the O/l "bias cancellation" argument was wrong (covariance with V survives).
// R10: cvtpk with +0x8000 bit pre-bias -> round-half-up (==RNE except ties),
// 3 VALU/pair vs ~10 manual, restoring R7-level accuracy with most of the R8
// VALU saving. Og store stays manual RNE. Skeleton identical to R7 (92.5us
// verified): 128-key tiles, K+V dbuf 64KB, counted vmcnt(4), hoisted base+imm
// LDS reads, T15 deferred last chunk, l-sum via ones-row MFMA, fz zero-C.
__global__ __launch_bounds__(512)
void flash_attn(const short* __restrict__ QKb, const short* __restrict__ Vt,
                short* __restrict__ Og)
{
    constexpr int L = 2048, LQ = 1280, HD = 64;
    constexpr int NT = L / 128;                              // 16 key-tiles of 128
    // layout per buf: Ks [128 perm-rows][64 d] (8192 sh) | Vs [64 d][128 keys] (8192 sh)
    __shared__ __attribute__((aligned(16))) short smem[2 * 16384]; // 64 KB

    const int t = threadIdx.x, lane = t & 63, w = t >> 6;    // w = 0..7
    const int lr = lane & 15, quad = lane >> 4;
    const int qt = blockIdx.x, h = blockIdx.y, b = blockIdx.z;
    const int kh = h >> 2;
    const int q0 = qt * 128;
    const int kcol = 1024 + kh * HD;

    // Q B-frags (wave owns q-cols w*16..w*16+15 of S^T / O^T)
    sh8 qf[2];
#pragma unroll
    for (int ks = 0; ks < 2; ++ks)
        qf[ks] = *reinterpret_cast<const sh8*>(
            QKb + (size_t)(b * L + q0 + w * 16 + lr) * LQ + h * HD + ks * 32 + quad * 8);

    f4v oT[4] = {};
    f4v lacc = {};                                   // denominator via MFMA ones-row
    const f4v fz = {};                               // persistent zero C-operand
    sh8 ones;
#pragma unroll
    for (int i = 0; i < 8; ++i) ones[i] = (short)0x3F80;   // bf16 1.0

    // hoisted LDS read bases: lane-dependent, tile-invariant. Per-tile reads are
    // base + compile-time imm (Ks: +buf*16384 + (half*4+nl)*1024; Vs: +8192 + m*2048).
    const int f7 = lr & 7, f15 = lr & 15;
    const short* const Ka0 = &smem[lr * 64 + ((quad ^ f7) << 3)];
    const short* const Ka1 = &smem[lr * 64 + (((4 + quad) ^ f7) << 3)];
    const short* const Vr[4] = {
        &smem[8192 + lr * 128 + (((0  + quad) ^ f15) << 3)],
        &smem[8192 + lr * 128 + (((4  + quad) ^ f15) << 3)],
        &smem[8192 + lr * 128 + (((8  + quad) ^ f15) << 3)],
        &smem[8192 + lr * 128 + (((12 + quad) ^ f15) << 3)] };

    // staging pointers, advanced by fixed stride per tile
    const int r8 = lane >> 3, g8 = lane & 7;        // K staging: row-in-seg, chunk
    const int v_r4 = lane >> 4, v_g = lane & 15;    // V staging: row-in-seg, chunk
    const short* Vbase = Vt + (size_t)kh * HD * 8192;
    const short* Kp[2];
    const short* Vp[2];
#pragma unroll
    for (int p = 0; p < 2; ++p) {
        const int s = 2 * w + p;
        const int rk = s * 8 + r8;                   // perm-row 0..127
        const int mm = rk & 15;
        const int key = ((rk >> 5) << 5) + ((mm >> 2) << 3) + (((rk >> 4) & 1) << 2) + (mm & 3);
        const int gk = g8 ^ (rk & 7);
        Kp[p] = QKb + (size_t)(b * L + key) * LQ + kcol + gk * 8;
        const int rv = s * 4 + v_r4;                 // d-row 0..63
        const int gv = v_g ^ (rv & 15);
        Vp[p] = Vbase + (size_t)rv * 8192 + b * L + gv * 8;
    }

    // stage one 128-key tile (K + V) into buf; 4 glds16 per thread per tile
    auto stage = [&](int buf) {
        short* Ks = smem + buf * 16384;
        short* Vs = Ks + 8192;
#pragma unroll
        for (int p = 0; p < 2; ++p) {
            glds16(Kp[p], &Ks[(2 * w + p) * 512]);
            Kp[p] += 128 * LQ;                       // next 128 keys (token rows)
            glds16(Vp[p], &Vs[(2 * w + p) * 512]);
            Vp[p] += 128;                            // next 128 keys (within V^T row)
        }
    };

    // deferred-chunk state (tile kt's c3, executed at top of tile kt+1)
    f4v stD0, stD1;
    sh8 vfD[4];

    // softmax+PV for one 32-key chunk (register-only given s0,s1,vf)
    auto smpv = [&](const f4v& s0, const f4v& s1, const sh8* vf) {
        f4v e0, e1;
#pragma unroll
        for (int i = 0; i < 4; ++i) {
            e0[i] = EXP2(s0[i]);
            e1[i] = EXP2(s1[i]);
        }
        u4v pu = { cvtpk_rhu(e0[0], e0[1]), cvtpk_rhu(e0[2], e0[3]),
                   cvtpk_rhu(e1[0], e1[1]), cvtpk_rhu(e1[2], e1[3]) };
        sh8 pf = __builtin_bit_cast(sh8, pu);
        __builtin_amdgcn_s_setprio(1);
        lacc = __builtin_amdgcn_mfma_f32_16x16x32_bf16(ones, pf, lacc, 0, 0, 0);
#pragma unroll
        for (int m = 0; m < 4; ++m)
            oT[m] = __builtin_amdgcn_mfma_f32_16x16x32_bf16(vf[m], pf, oT[m], 0, 0, 0);
        __builtin_amdgcn_s_setprio(0);
    };

    auto body = [&](int buf, int kt) {
        if (kt + 1 < NT) {
            stage(buf ^ 1);                          // issue next tile early
            // outstanding: cur tile 4 + next tile 4 -> wait until cur landed
            asm volatile("s_waitcnt vmcnt(4)" ::: "memory");
        } else {
            asm volatile("s_waitcnt vmcnt(0)" ::: "memory");
        }
        __builtin_amdgcn_s_barrier();                // publish: tile kt ready
        asm volatile("" ::: "memory");

        const int kb = buf * 16384;                  // compile-time after unroll

        // deferred c3 of previous tile: register-only, overlaps this tile's
        // ds_read latency + barrier edge
        if (kt) smpv(stD0, stD1, vfD);

        // S^T = K·Q^T, both halves (16 MFMA); first MFMA takes fz as C (no init movs)
        f4v stA[4], stB[4];
        __builtin_amdgcn_s_setprio(1);
#pragma unroll
        for (int nl = 0; nl < 4; ++nl) {
            sh8 a0 = *reinterpret_cast<const sh8*>(Ka0 + kb + nl * 1024);
            sh8 a1 = *reinterpret_cast<const sh8*>(Ka1 + kb + nl * 1024);
            stA[nl] = __builtin_amdgcn_mfma_f32_16x16x32_bf16(a0, qf[0], fz, 0, 0, 0);
            stA[nl] = __builtin_amdgcn_mfma_f32_16x16x32_bf16(a1, qf[1], stA[nl], 0, 0, 0);
        }
#pragma unroll
        for (int nl = 0; nl < 4; ++nl) {
            sh8 a0 = *reinterpret_cast<const sh8*>(Ka0 + kb + (4 + nl) * 1024);
            sh8 a1 = *reinterpret_cast<const sh8*>(Ka1 + kb + (4 + nl) * 1024);
            stB[nl] = __builtin_amdgcn_mfma_f32_16x16x32_bf16(a0, qf[0], fz, 0, 0, 0);
            stB[nl] = __builtin_amdgcn_mfma_f32_16x16x32_bf16(a1, qf[1], stB[nl], 0, 0, 0);
        }
        __builtin_amdgcn_s_setprio(0);

        // chunks c0..c2 in place
        {
            sh8 vf[4];
#pragma unroll
            for (int m = 0; m < 4; ++m) vf[m] = *reinterpret_cast<const sh8*>(Vr[0] + kb + m * 2048);
            smpv(stA[0], stA[1], vf);
#pragma unroll
            for (int m = 0; m < 4; ++m) vf[m] = *reinterpret_cast<const sh8*>(Vr[1] + kb + m * 2048);
            smpv(stA[2], stA[3], vf);
#pragma unroll
            for (int m = 0; m < 4; ++m) vf[m] = *reinterpret_cast<const sh8*>(Vr[2] + kb + m * 2048);
            smpv(stB[0], stB[1], vf);
        }

        // save c3 for deferred execution
#pragma unroll
        for (int m = 0; m < 4; ++m)
            vfD[m] = *reinterpret_cast<const sh8*>(Vr[3] + kb + m * 2048);
        stD0 = stB[2]; stD1 = stB[3];

        asm volatile("s_waitcnt lgkmcnt(0)" ::: "memory");  // vfD + all reads landed
        __builtin_amdgcn_s_barrier();                // release: buf may be restaged
        asm volatile("" ::: "memory");
    };

    stage(0);                                        // prologue prefetch
#pragma unroll 1
    for (int kt = 0; kt < NT; kt += 2) {
        body(0, kt);
        body(1, kt + 1);
    }
    smpv(stD0, stD1, vfD);                           // final deferred chunk

    // normalize + store O^T -> Og[token][h*64+d].  l = lacc[i] (rows identical).
    // Manual RNE here (cvtpk truncation at |Og|~1 broke absmax in R8).
    {
        const float inv = 1.0f / lacc[0];
        const size_t tok = (size_t)b * L + q0 + w * 16 + lr;
        short* op = Og + tok * 1024 + h * HD + quad * 4;
#pragma unroll
        for (int m = 0; m < 4; ++m) {
            u2v pk2 = { pk_bf16(oT[m][0] * inv, oT[m][1] * inv),
                        pk_bf16(oT[m][2] * inv, oT[m][3] * inv) };
            *reinterpret_cast<u2v*>(op + m * 16) = pk2;
        }
    }
}

extern "C" void kernel_launch(void* const* d_in, const int* in_sizes, int n_in,
                              void* d_out, int out_size, void* d_ws, size_t ws_size,
                              hipStream_t stream)
{
    (void)in_sizes; (void)n_in; (void)out_size; (void)ws_size;
    const float* x  = (const float*)d_in[0];
    const float* Wq = (const float*)d_in[1];
    const float* bq = (const float*)d_in[2];
    const float* Wk = (const float*)d_in[3];
    const float* bk = (const float*)d_in[4];
    const float* Wv = (const float*)d_in[5];
    const float* bv = (const float*)d_in[6];
    const float* Wo = (const float*)d_in[7];
    const float* bo = (const float*)d_in[8];
    float* out = (float*)d_out;

    char* ws = (char*)d_ws;
    short* xb   = (short*)(ws);                     // 8192x1024 bf16 = 16 MB
    short* Ob   = (short*)(ws);                     // aliases xb (dead after proj)
    short* Wqkb = (short*)(ws + 16777216);          // 1280x1024 bf16 = 2.5 MB
    short* Wvb  = (short*)(ws + 19398656);          // 256x1024 bf16 = 512 KB
    short* Wob  = (short*)(ws + 19922944);          // 1024x1024 bf16 = 2 MB
    float* bqk  = (float*)(ws + 22020096);          // 1280 fp32
    float* bvf  = (float*)(ws + 22025216);          // 256 fp32
    short* Vt   = (short*)(ws + 25165824);          // 256x8192 bf16 = 4 MB (V^T)
    short* QKb  = (short*)d_out;                    // 8192x1280 bf16 = 20 MB scratch

    pack_all<<<10754, 256, 0, stream>>>(x, Wq, Wk, Wv, Wo, bq, bk, bv,
                                        xb, Wqkb, Wvb, Wob, bqk, bvf);
    proj_fused<<<768, 256, 0, stream>>>(xb, Wqkb, bqk, QKb, Wvb, bvf, Vt);
    flash_attn<<<dim3(16, 16, 4), 512, 0, stream>>>(QKb, Vt, Ob);
    gemm_out<<<dim3(8, 64), 256, 0, stream>>>(Ob, Wob, bo, out, 8192, 1024, 1024);
}

// Round 11
// 235.854 us; speedup vs baseline: 1.1206x; 1.0454x over previous
//
#include <hip/hip_runtime.h>
#include <hip/hip_bf16.h>

typedef __attribute__((ext_vector_type(8))) short sh8;
typedef __attribute__((ext_vector_type(4))) short sh4;
typedef __attribute__((ext_vector_type(4))) float f4v;
typedef __attribute__((ext_vector_type(4))) unsigned u4v;
typedef __attribute__((ext_vector_type(2))) unsigned u2v;

#define SCALE_Q 0.1803368801f   // 0.125 * log2(e): folds softmax scale AND exp->exp2

__device__ __forceinline__ short f2bf(float f) {
    unsigned u = __builtin_bit_cast(unsigned, f);
    u += 0x7fffu + ((u >> 16) & 1u);   // RNE
    return (short)(u >> 16);
}

// manual RNE pack (lo=a, hi=b) — used for the Og store (full RNE, R8/R9 lesson)
__device__ __forceinline__ unsigned pk_bf16(float a, float b) {
    return (unsigned)(unsigned short)f2bf(a) | ((unsigned)(unsigned short)f2bf(b) << 16);
}

// gfx950 v_cvt_pk_bf16_f32 TRUNCATES (RTZ; R8/R9 empirical). Pre-biasing the
// float bits by +0x8000 turns trunc into round-half-up (== RNE except exact
// ties, <=0.5 ulp, unbiased). 3 VALU per pair vs ~10 manual. P>=0, no sign edge.
__device__ __forceinline__ unsigned cvtpk_rhu(float a, float b) {
    float fa = __builtin_bit_cast(float, __builtin_bit_cast(unsigned, a) + 0x8000u);
    float fb = __builtin_bit_cast(float, __builtin_bit_cast(unsigned, b) + 0x8000u);
    unsigned r;
    asm("v_cvt_pk_bf16_f32 %0, %1, %2" : "=v"(r) : "v"(fa), "v"(fb));
    return r;
}

#if __has_builtin(__builtin_amdgcn_exp2f)
#define EXP2(x) __builtin_amdgcn_exp2f(x)
#else
#define EXP2(x) exp2f(x)
#endif

__device__ __forceinline__ void glds16(const short* g, short* l) {
    __builtin_amdgcn_global_load_lds(
        (const __attribute__((address_space(1))) void*)g,
        (__attribute__((address_space(3))) void*)l, 16, 0, 0);
}

// ---------------- pack: fp32 -> bf16 conversions + weight fusion ----------------
// vec4 regions: x->xb | Wq->Wqkb(scaled) | Wk->Wqkb+1M | Wv->Wvb | Wo->Wob | biases
__global__ __launch_bounds__(256)
void pack_all(const float* __restrict__ x,  const float* __restrict__ Wq,
              const float* __restrict__ Wk, const float* __restrict__ Wv,
              const float* __restrict__ Wo, const float* __restrict__ bq,
              const float* __restrict__ bk, const float* __restrict__ bv,
              short* __restrict__ xb, short* __restrict__ Wqkb,
              short* __restrict__ Wvb, short* __restrict__ Wob,
              float* __restrict__ bqk, float* __restrict__ bvf)
{
    const long idx = (long)blockIdx.x * 256 + threadIdx.x;
    if (idx >= 2752896) return;
    const float* src; short* dst; float sc = 1.0f; long off;
    if (idx < 2097152)       { off = idx;           src = x;  dst = xb; }
    else if (idx < 2359296)  { off = idx - 2097152; src = Wq; dst = Wqkb;           sc = SCALE_Q; }
    else if (idx < 2424832)  { off = idx - 2359296; src = Wk; dst = Wqkb + 1048576; }
    else if (idx < 2490368)  { off = idx - 2424832; src = Wv; dst = Wvb; }
    else if (idx < 2752512)  { off = idx - 2490368; src = Wo; dst = Wob; }
    else {
        long j = idx - 2752512;  // 0..383
        const float* bs; float* bd; float s2 = 1.0f;
        if (j < 256)      { bs = bq + j * 4;         bd = bqk + j * 4;          s2 = SCALE_Q; }
        else if (j < 320) { bs = bk + (j - 256) * 4; bd = bqk + 1024 + (j - 256) * 4; }
        else              { bs = bv + (j - 320) * 4; bd = bvf + (j - 320) * 4; }
        f4v v = *reinterpret_cast<const f4v*>(bs);
        f4v o = { v[0] * s2, v[1] * s2, v[2] * s2, v[3] * s2 };
        *reinterpret_cast<f4v*>(bd) = o;
        return;
    }
    f4v v = *reinterpret_cast<const f4v*>(src + off * 4);
    sh4 o; o[0] = f2bf(v[0] * sc); o[1] = f2bf(v[1] * sc);
    o[2] = f2bf(v[2] * sc); o[3] = f2bf(v[3] * sc);
    *reinterpret_cast<sh4*>(dst + off * 4) = o;
}

// ---------------- fused projection: QK GEMM + V-transposed GEMM, one grid ----------------
// Blocks 0..639:   QKb[8192][1280] = xb[8192][1024] · Wqkb[1280][1024]^T + bqk (col bias)
// Blocks 640..767: Vt [256][8192]  = Wvb[256][1024] · xb[8192][1024]^T  + bvf (row bias)
// R11: T1 bijective chunked XCD swizzle per job (640%8==0, 128%8==0): XCD k gets a
// CONSECUTIVE id chunk -> B-panel (Wqkb 2.5MB / xb panels) stays L2-resident per XCD.
__global__ __launch_bounds__(256)
void proj_fused(const short* __restrict__ xb, const short* __restrict__ Wqkb,
                const float* __restrict__ bqk, short* __restrict__ QKb,
                const short* __restrict__ Wvb, const float* __restrict__ bvf,
                short* __restrict__ Vt)
{
    constexpr int K = 1024;
    __shared__ __attribute__((aligned(16))) short As[128 * 32];
    __shared__ __attribute__((aligned(16))) short Bs[128 * 32];

    const int t = threadIdx.x, lane = t & 63, w = t >> 6;
    const int lr = lane & 15, quad = lane >> 4;
    const int wm = (w >> 1) * 64, wn = (w & 1) * 64;
    const int sr = lane >> 2, sc = lane & 3;

    const int hw = blockIdx.x;
    int id;
    if (hw < 640) id = (hw & 7) * 80 + (hw >> 3);            // QK job: chunk 80/XCD
    else          id = 640 + ((hw - 640) & 7) * 16 + ((hw - 640) >> 3); // V job: chunk 16/XCD
    const short *A, *B; const float* bias; short* C;
    int m0, n0, N; bool brow;
    if (id < 640) {
        A = xb;  B = Wqkb; bias = bqk; C = QKb; N = 1280;
        m0 = (id / 10) * 128; n0 = (id % 10) * 128; brow = false;
    } else {
        const int v = id - 640;
        A = Wvb; B = xb;   bias = bvf; C = Vt;  N = 8192;
        m0 = (v >> 6) * 128; n0 = (v & 63) * 128; brow = true;
    }

    f4v acc[4][4] = {};

    for (int kb = 0; kb < K; kb += 32) {
#pragma unroll
        for (int p = 0; p < 2; ++p) {
            const int s = 2 * w + p;
            const int r = s * 16 + sr;
            const int g = sc ^ ((r >> 1) & 3);
            glds16(A + (size_t)(m0 + r) * K + kb + g * 8, &As[s * 512]);
            glds16(B + (size_t)(n0 + r) * K + kb + g * 8, &Bs[s * 512]);
        }
        __syncthreads();
        sh8 af[4], bfr[4];
#pragma unroll
        for (int i = 0; i < 4; ++i) {
            const int ra = wm + i * 16 + lr;
            af[i] = *reinterpret_cast<const sh8*>(&As[ra * 32 + ((quad ^ ((ra >> 1) & 3)) << 3)]);
            const int rb = wn + i * 16 + lr;
            bfr[i] = *reinterpret_cast<const sh8*>(&Bs[rb * 32 + ((quad ^ ((rb >> 1) & 3)) << 3)]);
        }
#pragma unroll
        for (int mi = 0; mi < 4; ++mi)
#pragma unroll
            for (int ni = 0; ni < 4; ++ni)
                acc[mi][ni] = __builtin_amdgcn_mfma_f32_16x16x32_bf16(af[mi], bfr[ni], acc[mi][ni], 0, 0, 0);
        __syncthreads();
    }

#pragma unroll
    for (int mi = 0; mi < 4; ++mi) {
        const int row = m0 + wm + mi * 16 + quad * 4;
        f4v br4 = {};
        if (brow) br4 = *reinterpret_cast<const f4v*>(&bias[row]);
#pragma unroll
        for (int ni = 0; ni < 4; ++ni) {
            const int col = n0 + wn + ni * 16 + lr;
            const float bc = brow ? 0.f : bias[col];
#pragma unroll
            for (int i = 0; i < 4; ++i) {
                const float v = acc[mi][ni][i] + (brow ? br4[i] : bc);
                C[(size_t)(row + i) * N + col] = f2bf(v);
            }
        }
    }
}

// ---------------- O-projection GEMM: out[M,N] = A[M,K] · W[N,K]^T + bias (fp32 out) ----------------
// R11: T1 chunked XCD swizzle (512%8==0): XCD k owns 64 consecutive ids ->
// Wob (2MB) L2-resident per XCD; A-panels read once per XCD.
__global__ __launch_bounds__(256)
void gemm_out(const short* __restrict__ A, const short* __restrict__ B,
              const float* __restrict__ bias, float* __restrict__ Cv,
              int M, int N, int K)
{
    __shared__ __attribute__((aligned(16))) short As[128 * 32];
    __shared__ __attribute__((aligned(16))) short Bs[128 * 32];

    const int t = threadIdx.x, lane = t & 63, w = t >> 6;
    const int lr = lane & 15, quad = lane >> 4;
    const int hw = blockIdx.x + 8 * blockIdx.y;              // 0..511
    const int id = (hw & 7) * 64 + (hw >> 3);                // chunk 64/XCD
    const int m0 = (id >> 3) * 128, n0 = (id & 7) * 128;
    const int wm = (w >> 1) * 64, wn = (w & 1) * 64;
    const int sr = lane >> 2, sc = lane & 3;

    f4v acc[4][4] = {};

    for (int kb = 0; kb < K; kb += 32) {
#pragma unroll
        for (int p = 0; p < 2; ++p) {
            const int s = 2 * w + p;
            const int r = s * 16 + sr;
            const int g = sc ^ ((r >> 1) & 3);
            glds16(A + (size_t)(m0 + r) * K + kb + g * 8, &As[s * 512]);
            glds16(B + (size_t)(n0 + r) * K + kb + g * 8, &Bs[s * 512]);
        }
        __syncthreads();
        sh8 af[4], bfr[4];
#pragma unroll
        for (int i = 0; i < 4; ++i) {
            const int ra = wm + i * 16 + lr;
            af[i] = *reinterpret_cast<const sh8*>(&As[ra * 32 + ((quad ^ ((ra >> 1) & 3)) << 3)]);
            const int rb = wn + i * 16 + lr;
            bfr[i] = *reinterpret_cast<const sh8*>(&Bs[rb * 32 + ((quad ^ ((rb >> 1) & 3)) << 3)]);
        }
#pragma unroll
        for (int mi = 0; mi < 4; ++mi)
#pragma unroll
            for (int ni = 0; ni < 4; ++ni)
                acc[mi][ni] = __builtin_amdgcn_mfma_f32_16x16x32_bf16(af[mi], bfr[ni], acc[mi][ni], 0, 0, 0);
        __syncthreads();
    }

#pragma unroll
    for (int ni = 0; ni < 4; ++ni) {
        const int col = n0 + wn + ni * 16 + lr;
        const float bv = bias[col];
#pragma unroll
        for (int mi = 0; mi < 4; ++mi) {
            const int row = m0 + wm + mi * 16 + quad * 4;
#pragma unroll
            for (int i = 0; i < 4; ++i)
                Cv[(size_t)(row + i) * N + col] = acc[mi][ni][i] + bv;
        }
    }
}

// ---------------- flash attention: S^T/O^T formulation, P in registers ----------------
// QKb [8192][1280]: Q cols 0..1023 (pre-scaled by 0.125*log2e), K cols 1024..1279.
// Vt [256][8192]: V^T, token-contiguous rows.
// R10 verified at 80.8us (cvtpk_rhu P-pack). R11 adds ONLY the T1 XCD swizzle:
// flat hw -> chunked id so each XCD's 128-block chunk shares (b, kh) K/V streams
// (2 x 512KB, L2-resident) instead of scattering all 16 streams over all XCDs.
// Skeleton unchanged: 128-key tiles, K+V dbuf 64KB, counted vmcnt(4), hoisted
// base+imm LDS reads, T15 deferred last chunk, l-sum via ones-row MFMA, fz zero-C.
__global__ __launch_bounds__(512)
void flash_attn(const short* __restrict__ QKb, const short* __restrict__ Vt,
                short* __restrict__ Og)
{
    constexpr int L = 2048, LQ = 1280, HD = 64;
    constexpr int NT = L / 128;                              // 16 key-tiles of 128
    // layout per buf: Ks [128 perm-rows][64 d] (8192 sh) | Vs [64 d][128 keys] (8192 sh)
    __shared__ __attribute__((aligned(16))) short smem[2 * 16384]; // 64 KB

    const int t = threadIdx.x, lane = t & 63, w = t >> 6;    // w = 0..7
    const int lr = lane & 15, quad = lane >> 4;
    const int hw = blockIdx.x + 16 * blockIdx.y + 256 * blockIdx.z; // 0..1023
    const int id = (hw & 7) * 128 + (hw >> 3);               // chunk 128/XCD
    const int qt = id & 15, h = (id >> 4) & 15, b = id >> 8;
    const int kh = h >> 2;
    const int q0 = qt * 128;
    const int kcol = 1024 + kh * HD;

    // Q B-frags (wave owns q-cols w*16..w*16+15 of S^T / O^T)
    sh8 qf[2];
#pragma unroll
    for (int ks = 0; ks < 2; ++ks)
        qf[ks] = *reinterpret_cast<const sh8*>(
            QKb + (size_t)(b * L + q0 + w * 16 + lr) * LQ + h * HD + ks * 32 + quad * 8);

    f4v oT[4] = {};
    f4v lacc = {};                                   // denominator via MFMA ones-row
    const f4v fz = {};                               // persistent zero C-operand
    sh8 ones;
#pragma unroll
    for (int i = 0; i < 8; ++i) ones[i] = (short)0x3F80;   // bf16 1.0

    // hoisted LDS read bases: lane-dependent, tile-invariant. Per-tile reads are
    // base + compile-time imm (Ks: +buf*16384 + (half*4+nl)*1024; Vs: +8192 + m*2048).
    const int f7 = lr & 7, f15 = lr & 15;
    const short* const Ka0 = &smem[lr * 64 + ((quad ^ f7) << 3)];
    const short* const Ka1 = &smem[lr * 64 + (((4 + quad) ^ f7) << 3)];
    const short* const Vr[4] = {
        &smem[8192 + lr * 128 + (((0  + quad) ^ f15) << 3)],
        &smem[8192 + lr * 128 + (((4  + quad) ^ f15) << 3)],
        &smem[8192 + lr * 128 + (((8  + quad) ^ f15) << 3)],
        &smem[8192 + lr * 128 + (((12 + quad) ^ f15) << 3)] };

    // staging pointers, advanced by fixed stride per tile
    const int r8 = lane >> 3, g8 = lane & 7;        // K staging: row-in-seg, chunk
    const int v_r4 = lane >> 4, v_g = lane & 15;    // V staging: row-in-seg, chunk
    const short* Vbase = Vt + (size_t)kh * HD * 8192;
    const short* Kp[2];
    const short* Vp[2];
#pragma unroll
    for (int p = 0; p < 2; ++p) {
        const int s = 2 * w + p;
        const int rk = s * 8 + r8;                   // perm-row 0..127
        const int mm = rk & 15;
        const int key = ((rk >> 5) << 5) + ((mm >> 2) << 3) + (((rk >> 4) & 1) << 2) + (mm & 3);
        const int gk = g8 ^ (rk & 7);
        Kp[p] = QKb + (size_t)(b * L + key) * LQ + kcol + gk * 8;
        const int rv = s * 4 + v_r4;                 // d-row 0..63
        const int gv = v_g ^ (rv & 15);
        Vp[p] = Vbase + (size_t)rv * 8192 + b * L + gv * 8;
    }

    // stage one 128-key tile (K + V) into buf; 4 glds16 per thread per tile
    auto stage = [&](int buf) {
        short* Ks = smem + buf * 16384;
        short* Vs = Ks + 8192;
#pragma unroll
        for (int p = 0; p < 2; ++p) {
            glds16(Kp[p], &Ks[(2 * w + p) * 512]);
            Kp[p] += 128 * LQ;                       // next 128 keys (token rows)
            glds16(Vp[p], &Vs[(2 * w + p) * 512]);
            Vp[p] += 128;                            // next 128 keys (within V^T row)
        }
    };

    // deferred-chunk state (tile kt's c3, executed at top of tile kt+1)
    f4v stD0, stD1;
    sh8 vfD[4];

    // softmax+PV for one 32-key chunk (register-only given s0,s1,vf)
    auto smpv = [&](const f4v& s0, const f4v& s1, const sh8* vf) {
        f4v e0, e1;
#pragma unroll
        for (int i = 0; i < 4; ++i) {
            e0[i] = EXP2(s0[i]);
            e1[i] = EXP2(s1[i]);
        }
        u4v pu = { cvtpk_rhu(e0[0], e0[1]), cvtpk_rhu(e0[2], e0[3]),
                   cvtpk_rhu(e1[0], e1[1]), cvtpk_rhu(e1[2], e1[3]) };
        sh8 pf = __builtin_bit_cast(sh8, pu);
        __builtin_amdgcn_s_setprio(1);
        lacc = __builtin_amdgcn_mfma_f32_16x16x32_bf16(ones, pf, lacc, 0, 0, 0);
#pragma unroll
        for (int m = 0; m < 4; ++m)
            oT[m] = __builtin_amdgcn_mfma_f32_16x16x32_bf16(vf[m], pf, oT[m], 0, 0, 0);
        __builtin_amdgcn_s_setprio(0);
    };

    auto body = [&](int buf, int kt) {
        if (kt + 1 < NT) {
            stage(buf ^ 1);                          // issue next tile early
            // outstanding: cur tile 4 + next tile 4 -> wait until cur landed
            asm volatile("s_waitcnt vmcnt(4)" ::: "memory");
        } else {
            asm volatile("s_waitcnt vmcnt(0)" ::: "memory");
        }
        __builtin_amdgcn_s_barrier();                // publish: tile kt ready
        asm volatile("" ::: "memory");

        const int kb = buf * 16384;                  // compile-time after unroll

        // deferred c3 of previous tile: register-only, overlaps this tile's
        // ds_read latency + barrier edge
        if (kt) smpv(stD0, stD1, vfD);

        // S^T = K·Q^T, both halves (16 MFMA); first MFMA takes fz as C (no init movs)
        f4v stA[4], stB[4];
        __builtin_amdgcn_s_setprio(1);
#pragma unroll
        for (int nl = 0; nl < 4; ++nl) {
            sh8 a0 = *reinterpret_cast<const sh8*>(Ka0 + kb + nl * 1024);
            sh8 a1 = *reinterpret_cast<const sh8*>(Ka1 + kb + nl * 1024);
            stA[nl] = __builtin_amdgcn_mfma_f32_16x16x32_bf16(a0, qf[0], fz, 0, 0, 0);
            stA[nl] = __builtin_amdgcn_mfma_f32_16x16x32_bf16(a1, qf[1], stA[nl], 0, 0, 0);
        }
#pragma unroll
        for (int nl = 0; nl < 4; ++nl) {
            sh8 a0 = *reinterpret_cast<const sh8*>(Ka0 + kb + (4 + nl) * 1024);
            sh8 a1 = *reinterpret_cast<const sh8*>(Ka1 + kb + (4 + nl) * 1024);
            stB[nl] = __builtin_amdgcn_mfma_f32_16x16x32_bf16(a0, qf[0], fz, 0, 0, 0);
            stB[nl] = __builtin_amdgcn_mfma_f32_16x16x32_bf16(a1, qf[1], stB[nl], 0, 0, 0);
        }
        __builtin_amdgcn_s_setprio(0);

        // chunks c0..c2 in place
        {
            sh8 vf[4];
#pragma unroll
            for (int m = 0; m < 4; ++m) vf[m] = *reinterpret_cast<const sh8*>(Vr[0] + kb + m * 2048);
            smpv(stA[0], stA[1], vf);
#pragma unroll
            for (int m = 0; m < 4; ++m) vf[m] = *reinterpret_cast<const sh8*>(Vr[1] + kb + m * 2048);
            smpv(stA[2], stA[3], vf);
#pragma unroll
            for (int m = 0; m < 4; ++m) vf[m] = *reinterpret_cast<const sh8*>(Vr[2] + kb + m * 2048);
            smpv(stB[0], stB[1], vf);
        }

        // save c3 for deferred execution
#pragma unroll
        for (int m = 0; m < 4; ++m)
            vfD[m] = *reinterpret_cast<const sh8*>(Vr[3] + kb + m * 2048);
        stD0 = stB[2]; stD1 = stB[3];

        asm volatile("s_waitcnt lgkmcnt(0)" ::: "memory");  // vfD + all reads landed
        __builtin_amdgcn_s_barrier();                // release: buf may be restaged
        asm volatile("" ::: "memory");
    };

    stage(0);                                        // prologue prefetch
#pragma unroll 1
    for (int kt = 0; kt < NT; kt += 2) {
        body(0, kt);
        body(1, kt + 1);
    }
    smpv(stD0, stD1, vfD);                           // final deferred chunk

    // normalize + store O^T -> Og[token][h*64+d].  l = lacc[i] (rows identical).
    // Manual RNE here (cvtpk truncation at |Og|~1 broke absmax in R8).
    {
        const float inv = 1.0f / lacc[0];
        const size_t tok = (size_t)b * L + q0 + w * 16 + lr;
        short* op = Og + tok * 1024 + h * HD + quad * 4;
#pragma unroll
        for (int m = 0; m < 4; ++m) {
            u2v pk2 = { pk_bf16(oT[m][0] * inv, oT[m][1] * inv),
                        pk_bf16(oT[m][2] * inv, oT[m][3] * inv) };
            *reinterpret_cast<u2v*>(op + m * 16) = pk2;
        }
    }
}

extern "C" void kernel_launch(void* const* d_in, const int* in_sizes, int n_in,
                              void* d_out, int out_size, void* d_ws, size_t ws_size,
                              hipStream_t stream)
{
    (void)in_sizes; (void)n_in; (void)out_size; (void)ws_size;
    const float* x  = (const float*)d_in[0];
    const float* Wq = (const float*)d_in[1];
    const float* bq = (const float*)d_in[2];
    const float* Wk = (const float*)d_in[3];
    const float* bk = (const float*)d_in[4];
    const float* Wv = (const float*)d_in[5];
    const float* bv = (const float*)d_in[6];
    const float* Wo = (const float*)d_in[7];
    const float* bo = (const float*)d_in[8];
    float* out = (float*)d_out;

    char* ws = (char*)d_ws;
    short* xb   = (short*)(ws);                     // 8192x1024 bf16 = 16 MB
    short* Ob   = (short*)(ws);                     // aliases xb (dead after proj)
    short* Wqkb = (short*)(ws + 16777216);          // 1280x1024 bf16 = 2.5 MB
    short* Wvb  = (short*)(ws + 19398656);          // 256x1024 bf16 = 512 KB
    short* Wob  = (short*)(ws + 19922944);          // 1024x1024 bf16 = 2 MB
    float* bqk  = (float*)(ws + 22020096);          // 1280 fp32
    float* bvf  = (float*)(ws + 22025216);          // 256 fp32
    short* Vt   = (short*)(ws + 25165824);          // 256x8192 bf16 = 4 MB (V^T)
    short* QKb  = (short*)d_out;                    // 8192x1280 bf16 = 20 MB scratch

    pack_all<<<10754, 256, 0, stream>>>(x, Wq, Wk, Wv, Wo, bq, bk, bv,
                                        xb, Wqkb, Wvb, Wob, bqk, bvf);
    proj_fused<<<768, 256, 0, stream>>>(xb, Wqkb, bqk, QKb, Wvb, bvf, Vt);
    flash_attn<<<dim3(16, 16, 4), 512, 0, stream>>>(QKb, Vt, Ob);
    gemm_out<<<dim3(8, 64), 256, 0, stream>>>(Ob, Wob, bo, out, 8192, 1024, 1024);
}